// Round 3
// baseline (655.973 us; speedup 1.0000x reference)
//
#include <hip/hip_runtime.h>
#include <cstdint>
#include <cstddef>

// ---------------------------------------------------------------------------
// KAN encode: x(4096,1024) -> KANLinear(1024->2048) -> KANLinear(2048->1024)
//             -> ReLU -> Dense(1024->512)+bias
// bf16 MFMA GEMMs over augmented K (9 channels per input feature).
// R10: R8 (8-phase) and R9 (counted-vmcnt) both proved schedule is not the
//      binding constraint (750-830 TF across 3 schedules). Keep R9 skeleton,
//      switch MFMA shape 16x16x32 -> 32x32x16:
//        - pipe ceiling 2075 -> 2495 TF (m06/m119, +20%)
//        - MFMA instr count halved (32 -> 16 per wave per K-step)
//        - same ds_read count/bytes (4 A + 8 W b128 per wave per K-step)
//        - ksub outermost: 8 independent MFMAs between acc reuses
//      A/B operand: row = lane&31, k = (lane>>5)*8 + j (verified pattern).
//      C/D: col = lane&31, row = (reg&3) + 8*(reg>>2) + 4*(lane>>5) (m74/m101).
// ---------------------------------------------------------------------------

typedef __bf16 bf16x8 __attribute__((ext_vector_type(8)));
typedef float floatx4 __attribute__((ext_vector_type(4)));
typedef float floatx16 __attribute__((ext_vector_type(16)));

#define BATCH 4096
#define DIN   1024
#define H0N   2048
#define H1N   1024
#define LOUT  512

// Workspace layout (bytes).
#define OFF_A0  ((size_t)0)           // bf16 4096*9216  = 75,497,472
#define OFF_W0  ((size_t)75497472)    // bf16 2048*9216  = 37,748,736
#define OFF_A1  ((size_t)0)           // bf16 4096*18432 = 150,994,944 (overlays A0+W0)
#define OFF_P0  ((size_t)150994944)   // f32 2*4096*2048 = 67,108,864
#define OFF_W1  ((size_t)218103808)   // bf16 1024*18432 = 37,748,736
#define OFF_P1  ((size_t)150994944)   // f32 4*4096*1024 = 67,108,864 (overlays P0)
#define OFF_H1R ((size_t)218103808)   // bf16 4096*1024  =  8,388,608 (overlays W1)
#define OFF_DW  ((size_t)226492416)   // bf16 512*1024   =  1,048,576

// --------------------------- spline bases ----------------------------------
__device__ __forceinline__ void bspline8(float x, float* out) {
    float b[11];
#pragma unroll
    for (int j = 0; j < 11; ++j) {
        float t0 = (j - 3) * 0.4f - 1.0f;
        float t1 = (j - 2) * 0.4f - 1.0f;
        b[j] = (x >= t0 && x < t1) ? 1.0f : 0.0f;
    }
#pragma unroll
    for (int k = 1; k <= 3; ++k) {
#pragma unroll
        for (int j = 0; j + k < 11; ++j) {
            float tj   = (j - 3) * 0.4f - 1.0f;
            float tj1  = (j - 2) * 0.4f - 1.0f;
            float tjk  = (j + k - 3) * 0.4f - 1.0f;
            float tjk1 = (j + k - 2) * 0.4f - 1.0f;
            float left  = (x - tj)   * (1.0f / (tjk - tj));
            float right = (tjk1 - x) * (1.0f / (tjk1 - tj1));
            b[j] = left * b[j] + right * b[j + 1];
        }
    }
#pragma unroll
    for (int j = 0; j < 8; ++j) out[j] = b[j];
}

// Store 256 threads * 9 bf16 via LDS as 288 coalesced 16B chunks.
__device__ __forceinline__ void coalesced_store9(__bf16* block_dst, const __bf16* vals) {
    __shared__ __bf16 sbuf[256 * 9];
    __bf16* p = &sbuf[threadIdx.x * 9];
#pragma unroll
    for (int j = 0; j < 9; ++j) p[j] = vals[j];
    __syncthreads();
    const uint4* src = (const uint4*)sbuf;
    uint4* dst = (uint4*)block_dst;
    dst[threadIdx.x] = src[threadIdx.x];
    if (threadIdx.x < 32) dst[256 + threadIdx.x] = src[256 + threadIdx.x];
}

__device__ __forceinline__ void act9(float v, __bf16* r) {
    float s = v / (1.0f + __expf(-v));
    float bb[8];
    bspline8(v, bb);
    r[0] = (__bf16)s;
#pragma unroll
    for (int j = 0; j < 8; ++j) r[1 + j] = (__bf16)bb[j];
}

__global__ void kan_act(const float* __restrict__ in, __bf16* __restrict__ out) {
    int base = blockIdx.x * 256;
    float v = in[base + threadIdx.x];
    __bf16 r[9];
    act9(v, r);
    coalesced_store9(out + (size_t)base * 9, r);
}

__global__ void kan_act_sum2(const float* __restrict__ pa, const float* __restrict__ pb,
                             __bf16* __restrict__ out) {
    int base = blockIdx.x * 256;
    int idx = base + threadIdx.x;
    float v = pa[idx] + pb[idx];
    __bf16 r[9];
    act9(v, r);
    coalesced_store9(out + (size_t)base * 9, r);
}

__global__ void relu_sum4(const float* __restrict__ p, size_t stride,
                          __bf16* __restrict__ out, int total4) {
    int idx = blockIdx.x * 256 + threadIdx.x;
    if (idx >= total4) return;
    const float4* p0 = (const float4*)p;
    const float4* p1 = (const float4*)(p + stride);
    const float4* p2 = (const float4*)(p + 2 * stride);
    const float4* p3 = (const float4*)(p + 3 * stride);
    float4 a = p0[idx], b = p1[idx], c = p2[idx], d = p3[idx];
    __bf16 r[4];
    r[0] = (__bf16)fmaxf(a.x + b.x + c.x + d.x, 0.0f);
    r[1] = (__bf16)fmaxf(a.y + b.y + c.y + d.y, 0.0f);
    r[2] = (__bf16)fmaxf(a.z + b.z + c.z + d.z, 0.0f);
    r[3] = (__bf16)fmaxf(a.w + b.w + c.w + d.w, 0.0f);
    *(uint2*)&out[(size_t)idx * 4] = *(uint2*)r;
}

__global__ void kan_wprep(const float* __restrict__ bw, const float* __restrict__ sw,
                          const float* __restrict__ ss, __bf16* __restrict__ out) {
    int base = blockIdx.x * 256;
    int idx = base + threadIdx.x;
    float b  = bw[idx];
    float sc = ss[idx];
    const float4* sv = (const float4*)(sw + (size_t)idx * 8);
    float4 a = sv[0], c = sv[1];
    __bf16 r[9];
    r[0] = (__bf16)b;
    r[1] = (__bf16)(a.x * sc); r[2] = (__bf16)(a.y * sc);
    r[3] = (__bf16)(a.z * sc); r[4] = (__bf16)(a.w * sc);
    r[5] = (__bf16)(c.x * sc); r[6] = (__bf16)(c.y * sc);
    r[7] = (__bf16)(c.z * sc); r[8] = (__bf16)(c.w * sc);
    coalesced_store9(out + (size_t)base * 9, r);
}

__global__ void f2bf(const float* __restrict__ in, __bf16* __restrict__ out,
                     int total) {
    int idx = blockIdx.x * 256 + threadIdx.x;
    if (idx < total) out[idx] = (__bf16)in[idx];
}

// --------------------------- staging helper --------------------------------
__device__ __forceinline__ void gload_lds16(const void* g, void* l) {
    __builtin_amdgcn_global_load_lds(
        (const __attribute__((address_space(1))) uint32_t*)g,
        (__attribute__((address_space(3))) uint32_t*)l, 16, 0, 0);
}

// Bank swizzle: LDS slot (row r, pos p) holds global chunk q = p ^ ((r>>1)&3).

// ---- pipelined MFMA GEMM: 256x128 tile, 4 waves (64x128 each), 2 blk/CU ---
// C(M,N) = A(M,K) @ W(N,K)^T, bf16 in, fp32 out (split-K partial per z).
// 3-deep cyclic LDS; per K-step: {stage slab s+2 | reads(s) | 16 MFMA 32x32 |
// s_waitcnt vmcnt(6) lgkmcnt(0) | s_barrier}.
__global__ __launch_bounds__(256, 2) void gemm_pipe(
    const __bf16* __restrict__ A, const __bf16* __restrict__ W,
    float* __restrict__ Cout, int M, int N, int K, int Ks) {
    constexpr int BK = 32;                    // 64 B LDS rows (4 x 16B chunks)
    __shared__ __bf16 As[3][256 * BK];        // 3 x 16 KB
    __shared__ __bf16 Ws[3][128 * BK];        // 3 x 8 KB

    const int tid  = threadIdx.x;
    const int lane = tid & 63;
    const int wave = tid >> 6;

    // XCD-aware swizzle (round-robin dispatch: id&7 = XCD)
    const int id    = (blockIdx.z * gridDim.y + blockIdx.y) * gridDim.x + blockIdx.x;
    const int mslab = gridDim.y >> 3;
    const int xcd   = id & 7;
    const int local = id >> 3;
    const int m_off = local % mslab;
    const int rest  = local / mslab;
    const int ntile = rest % gridDim.x;
    const int zt    = rest / gridDim.x;
    const int bm    = (xcd * mslab + m_off) * 256;
    const int bn    = ntile * 128;
    const int kbase = zt * Ks;

    const int wm  = wave * 64;
    const int l31 = lane & 31;
    const int kg  = lane >> 5;                 // k-group 0..1 (8 bf16 each)

    floatx16 acc[2][4] = {};

    auto stage = [&](int slot, int kstep) {
        const int kpos = kstep * BK;
#pragma unroll
        for (int i = 0; i < 4; ++i) {          // A: 1024 chunks of 16 B
            int c = i * 256 + tid;
            int r = c >> 2;
            int q = (c & 3) ^ ((r >> 1) & 3);  // swizzled source chunk
            gload_lds16(&A[(size_t)(bm + r) * K + kbase + kpos + q * 8],
                        &As[slot][(size_t)(i * 256 + wave * 64) * 8]);
        }
#pragma unroll
        for (int i = 0; i < 2; ++i) {          // W: 512 chunks
            int c = i * 256 + tid;
            int r = c >> 2;
            int q = (c & 3) ^ ((r >> 1) & 3);
            gload_lds16(&W[(size_t)(bn + r) * K + kbase + kpos + q * 8],
                        &Ws[slot][(size_t)(i * 256 + wave * 64) * 8]);
        }
    };

    // Fragment reads for 32x32x16: lane holds row = base + l31,
    // k = ksub*16 + kg*8 + j  -> 16B chunk index c = ksub*2 + kg.
    auto compute = [&](int slot) {
        bf16x8 af[2][2], wf[2][4];             // [ksub][frag]
#pragma unroll
        for (int ks = 0; ks < 2; ++ks) {
            const int c = ks * 2 + kg;
#pragma unroll
            for (int mt = 0; mt < 2; ++mt) {
                int r = wm + mt * 32 + l31;
                af[ks][mt] = *(const bf16x8*)
                    &As[slot][r * BK + ((c ^ ((r >> 1) & 3)) * 8)];
            }
#pragma unroll
            for (int nt = 0; nt < 4; ++nt) {
                int r = nt * 32 + l31;
                wf[ks][nt] = *(const bf16x8*)
                    &Ws[slot][r * BK + ((c ^ ((r >> 1) & 3)) * 8)];
            }
        }
        __builtin_amdgcn_s_setprio(1);
#pragma unroll
        for (int ks = 0; ks < 2; ++ks)         // ksub outermost: 8 indep MFMAs
#pragma unroll
            for (int mt = 0; mt < 2; ++mt)
#pragma unroll
                for (int nt = 0; nt < 4; ++nt)
                    acc[mt][nt] = __builtin_amdgcn_mfma_f32_32x32x16_bf16(
                        af[ks][mt], wf[ks][nt], acc[mt][nt], 0, 0, 0);
        __builtin_amdgcn_s_setprio(0);
    };

    const int NKs = Ks >> 5;                  // 32-wide K-steps

    // Prologue: stage slabs 0,1 (12 loads/wave); need slab 0 -> vmcnt(6).
    stage(0, 0);
    stage(1, 1);
    asm volatile("s_waitcnt vmcnt(6)" ::: "memory");
    __builtin_amdgcn_s_barrier();

    int sl = 0;
#pragma unroll 1
    for (int s = 0; s < NKs - 2; ++s) {
        int sln = sl + 2; if (sln >= 3) sln -= 3;
        stage(sln, s + 2);                    // DMA issues first, hides under compute
        compute(sl);
        // slab s+1 must be landed; stage(s+2)'s 6 loads stay in flight.
        asm volatile("s_waitcnt vmcnt(6) lgkmcnt(0)" ::: "memory");
        __builtin_amdgcn_s_barrier();
        sl = (sl == 2) ? 0 : sl + 1;
    }
    compute(sl);
    asm volatile("s_waitcnt vmcnt(0) lgkmcnt(0)" ::: "memory");
    __builtin_amdgcn_s_barrier();
    sl = (sl == 2) ? 0 : sl + 1;
    compute(sl);

    // C/D 32x32: col = l31, row = (reg&3) + 8*(reg>>2) + 4*kg
    float* Cz = Cout + (size_t)zt * M * N;
#pragma unroll
    for (int mt = 0; mt < 2; ++mt) {
#pragma unroll
        for (int nt = 0; nt < 4; ++nt) {
            int n = bn + nt * 32 + l31;
#pragma unroll
            for (int rg = 0; rg < 16; ++rg) {
                int m = bm + wm + mt * 32 + (rg & 3) + 8 * (rg >> 2) + 4 * kg;
                Cz[(size_t)m * N + n] = acc[mt][nt][rg];
            }
        }
    }
}

// ----------------- 128x128 MFMA GEMM (dense epilogue) ----------------------
__global__ __launch_bounds__(256) void gemm_dense(
    const __bf16* __restrict__ A, const __bf16* __restrict__ W,
    float* __restrict__ Cout, const float* __restrict__ bias,
    int M, int N, int K) {
    constexpr int BK = 32;
    __shared__ __bf16 As[2][128 * BK];
    __shared__ __bf16 Ws[2][128 * BK];

    const int tid  = threadIdx.x;
    const int lane = tid & 63;
    const int wave = tid >> 6;

    const int id    = blockIdx.y * gridDim.x + blockIdx.x;
    const int mslab = gridDim.y >> 3;
    const int xcd   = id & 7;
    const int local = id >> 3;
    const int m_off = local % mslab;
    const int ntile = local / mslab;
    const int bm    = (xcd * mslab + m_off) * 128;
    const int bn    = ntile * 128;

    const int wm = (wave >> 1) * 64;
    const int wn = (wave & 1) * 64;
    const int lr = lane & 15;
    const int kq = lane >> 4;
    const int kssw = (kq ^ ((lr >> 1) & 3)) * 8;

    floatx4 acc[4][4] = {};

    auto stage = [&](int buf, int kpos) {
#pragma unroll
        for (int i = 0; i < 2; ++i) {
            int c = i * 256 + tid;
            int r = c >> 2;
            int q = (c & 3) ^ ((r >> 1) & 3);
            gload_lds16(&A[(size_t)(bm + r) * K + kpos + q * 8],
                        &As[buf][(size_t)(i * 256 + wave * 64) * 8]);
            gload_lds16(&W[(size_t)(bn + r) * K + kpos + q * 8],
                        &Ws[buf][(size_t)(i * 256 + wave * 64) * 8]);
        }
    };

    auto compute = [&](int buf) {
        bf16x8 af[4], wf[4];
#pragma unroll
        for (int t = 0; t < 4; ++t) {
            af[t] = *(const bf16x8*)&As[buf][(wm + t * 16 + lr) * BK + kssw];
            wf[t] = *(const bf16x8*)&Ws[buf][(wn + t * 16 + lr) * BK + kssw];
        }
#pragma unroll
        for (int mt = 0; mt < 4; ++mt)
#pragma unroll
            for (int nt = 0; nt < 4; ++nt)
                acc[mt][nt] = __builtin_amdgcn_mfma_f32_16x16x32_bf16(
                    af[mt], wf[nt], acc[mt][nt], 0, 0, 0);
    };

    stage(0, 0);
    for (int k0 = 0; k0 < K; k0 += 2 * BK) {
        __syncthreads();
        if (k0 + BK < K) stage(1, k0 + BK);
        compute(0);
        __syncthreads();
        if (k0 + 2 * BK < K) stage(0, k0 + 2 * BK);
        compute(1);
    }

    const int col = lane & 15;
    const int rquad = (lane >> 4) * 4;
#pragma unroll
    for (int mt = 0; mt < 4; ++mt) {
#pragma unroll
        for (int nt = 0; nt < 4; ++nt) {
            int n = bn + wn + nt * 16 + col;
#pragma unroll
            for (int rg = 0; rg < 4; ++rg) {
                int m = bm + wm + mt * 16 + rquad + rg;
                Cout[(size_t)m * N + n] = acc[mt][nt][rg] + bias[n];
            }
        }
    }
}

// ---------------------------------------------------------------------------
extern "C" void kernel_launch(void* const* d_in, const int* in_sizes, int n_in,
                              void* d_out, int out_size, void* d_ws, size_t ws_size,
                              hipStream_t stream) {
    const float* x   = (const float*)d_in[0];
    const float* bw0 = (const float*)d_in[1];
    const float* sw0 = (const float*)d_in[2];
    const float* ss0 = (const float*)d_in[3];
    const float* bw1 = (const float*)d_in[4];
    const float* sw1 = (const float*)d_in[5];
    const float* ss1 = (const float*)d_in[6];
    const float* dw  = (const float*)d_in[7];
    const float* db  = (const float*)d_in[8];
    float* out = (float*)d_out;

    char* ws = (char*)d_ws;
    __bf16* A0  = (__bf16*)(ws + OFF_A0);
    __bf16* W0  = (__bf16*)(ws + OFF_W0);
    __bf16* A1  = (__bf16*)(ws + OFF_A1);
    float*  P0  = (float*)(ws + OFF_P0);
    __bf16* W1  = (__bf16*)(ws + OFF_W1);
    float*  P1  = (float*)(ws + OFF_P1);
    __bf16* h1r = (__bf16*)(ws + OFF_H1R);
    __bf16* dwb = (__bf16*)(ws + OFF_DW);

    // Layer 0: K = 9216, splitK=2 -> grid 16x16x2 = 512 blocks (2/CU)
    kan_wprep<<<(H0N * DIN) / 256, 256, 0, stream>>>(bw0, sw0, ss0, W0);
    kan_act<<<(BATCH * DIN) / 256, 256, 0, stream>>>(x, A0);
    gemm_pipe<<<dim3(H0N / 128, BATCH / 256, 2), 256, 0, stream>>>(
        A0, W0, P0, BATCH, H0N, DIN * 9, DIN * 9 / 2);

    // Layer 1: K = 18432, splitK=4 -> grid 8x16x4 = 512 blocks (2/CU)
    kan_wprep<<<(H1N * H0N) / 256, 256, 0, stream>>>(bw1, sw1, ss1, W1);
    kan_act_sum2<<<(BATCH * H0N) / 256, 256, 0, stream>>>(
        P0, P0 + (size_t)BATCH * H0N, A1);
    gemm_pipe<<<dim3(H1N / 128, BATCH / 256, 4), 256, 0, stream>>>(
        A1, W1, P1, BATCH, H1N, H0N * 9, H0N * 9 / 4);

    // relu(sum of 4 partials) -> bf16
    relu_sum4<<<(BATCH * H1N / 4) / 256, 256, 0, stream>>>(
        P1, (size_t)BATCH * H1N, h1r, BATCH * H1N / 4);

    // Dense: out = h1r @ dw^T + db  (K = 1024)
    f2bf<<<(LOUT * H1N) / 256, 256, 0, stream>>>(dw, dwb, LOUT * H1N);
    gemm_dense<<<dim3(LOUT / 128, BATCH / 128), 256, 0, stream>>>(
        h1r, dwb, out, db, BATCH, LOUT, H1N);
}

// Round 4
// 651.369 us; speedup vs baseline: 1.0071x; 1.0071x over previous
//
#include <hip/hip_runtime.h>
#include <cstdint>
#include <cstddef>

// ---------------------------------------------------------------------------
// KAN encode: x(4096,1024) -> KANLinear(1024->2048) -> KANLinear(2048->1024)
//             -> ReLU -> Dense(1024->512)+bias
// bf16 MFMA GEMMs over augmented K (9 channels per input feature).
// R11: R8/R9/R10 showed schedule is not binding (3 schedules, all ~35%
//      MfmaUtil; no pipe >50% in cycle model) and 32x32 MFMA conflicts with
//      the swizzle (R10: 1.4e7 bank conflicts). Diagnosis: LATENCY-bound at
//      8 waves/CU (2/SIMD). Fix occupancy: 128x128 tile (proven gemm_dense
//      structure, 2-deep LDS = 32 KB) x 1024 blocks = 4 blocks/CU =
//      16 waves/CU (4/SIMD). 16x16x32 MFMA (0-conflict swizzle) restored.
//      __launch_bounds__(256,4) caps unified VGPR+AGPR at 128/wave.
// ---------------------------------------------------------------------------

typedef __bf16 bf16x8 __attribute__((ext_vector_type(8)));
typedef float floatx4 __attribute__((ext_vector_type(4)));

#define BATCH 4096
#define DIN   1024
#define H0N   2048
#define H1N   1024
#define LOUT  512

// Workspace layout (bytes). Total = 227,540,992.
#define OFF_A0  ((size_t)0)           // bf16 4096*9216  = 75,497,472
#define OFF_W0  ((size_t)75497472)    // bf16 2048*9216  = 37,748,736
#define OFF_A1  ((size_t)0)           // bf16 4096*18432 = 150,994,944 (overlays A0+W0)
#define OFF_P0  ((size_t)150994944)   // f32 2*4096*2048 = 67,108,864
#define OFF_W1  ((size_t)218103808)   // bf16 1024*18432 = 37,748,736
#define OFF_P1  ((size_t)150994944)   // f32 4*4096*1024 = 67,108,864 (overlays P0)
#define OFF_H1R ((size_t)218103808)   // bf16 4096*1024  =  8,388,608 (overlays W1)
#define OFF_DW  ((size_t)226492416)   // bf16 512*1024   =  1,048,576

// --------------------------- spline bases ----------------------------------
__device__ __forceinline__ void bspline8(float x, float* out) {
    float b[11];
#pragma unroll
    for (int j = 0; j < 11; ++j) {
        float t0 = (j - 3) * 0.4f - 1.0f;
        float t1 = (j - 2) * 0.4f - 1.0f;
        b[j] = (x >= t0 && x < t1) ? 1.0f : 0.0f;
    }
#pragma unroll
    for (int k = 1; k <= 3; ++k) {
#pragma unroll
        for (int j = 0; j + k < 11; ++j) {
            float tj   = (j - 3) * 0.4f - 1.0f;
            float tj1  = (j - 2) * 0.4f - 1.0f;
            float tjk  = (j + k - 3) * 0.4f - 1.0f;
            float tjk1 = (j + k - 2) * 0.4f - 1.0f;
            float left  = (x - tj)   * (1.0f / (tjk - tj));
            float right = (tjk1 - x) * (1.0f / (tjk1 - tj1));
            b[j] = left * b[j] + right * b[j + 1];
        }
    }
#pragma unroll
    for (int j = 0; j < 8; ++j) out[j] = b[j];
}

// Store 256 threads * 9 bf16 via LDS as 288 coalesced 16B chunks.
__device__ __forceinline__ void coalesced_store9(__bf16* block_dst, const __bf16* vals) {
    __shared__ __bf16 sbuf[256 * 9];
    __bf16* p = &sbuf[threadIdx.x * 9];
#pragma unroll
    for (int j = 0; j < 9; ++j) p[j] = vals[j];
    __syncthreads();
    const uint4* src = (const uint4*)sbuf;
    uint4* dst = (uint4*)block_dst;
    dst[threadIdx.x] = src[threadIdx.x];
    if (threadIdx.x < 32) dst[256 + threadIdx.x] = src[256 + threadIdx.x];
}

__device__ __forceinline__ void act9(float v, __bf16* r) {
    float s = v / (1.0f + __expf(-v));
    float bb[8];
    bspline8(v, bb);
    r[0] = (__bf16)s;
#pragma unroll
    for (int j = 0; j < 8; ++j) r[1 + j] = (__bf16)bb[j];
}

__global__ void kan_act(const float* __restrict__ in, __bf16* __restrict__ out) {
    int base = blockIdx.x * 256;
    float v = in[base + threadIdx.x];
    __bf16 r[9];
    act9(v, r);
    coalesced_store9(out + (size_t)base * 9, r);
}

__global__ void kan_act_sum2(const float* __restrict__ pa, const float* __restrict__ pb,
                             __bf16* __restrict__ out) {
    int base = blockIdx.x * 256;
    int idx = base + threadIdx.x;
    float v = pa[idx] + pb[idx];
    __bf16 r[9];
    act9(v, r);
    coalesced_store9(out + (size_t)base * 9, r);
}

__global__ void relu_sum4(const float* __restrict__ p, size_t stride,
                          __bf16* __restrict__ out, int total4) {
    int idx = blockIdx.x * 256 + threadIdx.x;
    if (idx >= total4) return;
    const float4* p0 = (const float4*)p;
    const float4* p1 = (const float4*)(p + stride);
    const float4* p2 = (const float4*)(p + 2 * stride);
    const float4* p3 = (const float4*)(p + 3 * stride);
    float4 a = p0[idx], b = p1[idx], c = p2[idx], d = p3[idx];
    __bf16 r[4];
    r[0] = (__bf16)fmaxf(a.x + b.x + c.x + d.x, 0.0f);
    r[1] = (__bf16)fmaxf(a.y + b.y + c.y + d.y, 0.0f);
    r[2] = (__bf16)fmaxf(a.z + b.z + c.z + d.z, 0.0f);
    r[3] = (__bf16)fmaxf(a.w + b.w + c.w + d.w, 0.0f);
    *(uint2*)&out[(size_t)idx * 4] = *(uint2*)r;
}

__global__ void kan_wprep(const float* __restrict__ bw, const float* __restrict__ sw,
                          const float* __restrict__ ss, __bf16* __restrict__ out) {
    int base = blockIdx.x * 256;
    int idx = base + threadIdx.x;
    float b  = bw[idx];
    float sc = ss[idx];
    const float4* sv = (const float4*)(sw + (size_t)idx * 8);
    float4 a = sv[0], c = sv[1];
    __bf16 r[9];
    r[0] = (__bf16)b;
    r[1] = (__bf16)(a.x * sc); r[2] = (__bf16)(a.y * sc);
    r[3] = (__bf16)(a.z * sc); r[4] = (__bf16)(a.w * sc);
    r[5] = (__bf16)(c.x * sc); r[6] = (__bf16)(c.y * sc);
    r[7] = (__bf16)(c.z * sc); r[8] = (__bf16)(c.w * sc);
    coalesced_store9(out + (size_t)base * 9, r);
}

__global__ void f2bf(const float* __restrict__ in, __bf16* __restrict__ out,
                     int total) {
    int idx = blockIdx.x * 256 + threadIdx.x;
    if (idx < total) out[idx] = (__bf16)in[idx];
}

// --------------------------- staging helper --------------------------------
__device__ __forceinline__ void gload_lds16(const void* g, void* l) {
    __builtin_amdgcn_global_load_lds(
        (const __attribute__((address_space(1))) uint32_t*)g,
        (__attribute__((address_space(3))) uint32_t*)l, 16, 0, 0);
}

// Bank swizzle: LDS slot (row r, pos p) holds global chunk q = p ^ ((r>>1)&3).
// 16x16x32 frag reads (rows base+lr, lr=0..15, chunk kq) -> 2-way bank
// aliasing = free (verified SQ_LDS_BANK_CONFLICT == 0). Do NOT use with
// 32-row 32x32 frags (R10: 1.4e7 conflicts).

// ---- 128x128 MFMA GEMM, split-K partials, 4 blocks/CU --------------------
// C(M,N) partial = A(M,K) @ W(N,K)^T over this block's K-range.
// Proven gemm_dense structure: 2-deep LDS (32 KB), __syncthreads pipeline.
__global__ __launch_bounds__(256, 4) void gemm_t128(
    const __bf16* __restrict__ A, const __bf16* __restrict__ W,
    float* __restrict__ Cout, int M, int N, int K, int Ks) {
    constexpr int BK = 32;
    __shared__ __bf16 As[2][128 * BK];        // 2 x 8 KB
    __shared__ __bf16 Ws[2][128 * BK];        // 2 x 8 KB

    const int tid  = threadIdx.x;
    const int lane = tid & 63;
    const int wave = tid >> 6;

    // XCD-aware swizzle (round-robin dispatch: id&7 = XCD)
    const int id    = (blockIdx.z * gridDim.y + blockIdx.y) * gridDim.x + blockIdx.x;
    const int mslab = gridDim.y >> 3;
    const int xcd   = id & 7;
    const int local = id >> 3;
    const int m_off = local % mslab;
    const int rest  = local / mslab;
    const int ntile = rest % gridDim.x;
    const int zt    = rest / gridDim.x;
    const int bm    = (xcd * mslab + m_off) * 128;
    const int bn    = ntile * 128;
    const int kbase = zt * Ks;

    const int wm = (wave >> 1) * 64;
    const int wn = (wave & 1) * 64;
    const int lr = lane & 15;
    const int kq = lane >> 4;
    const int kssw = (kq ^ ((lr >> 1) & 3)) * 8;

    floatx4 acc[4][4] = {};

    auto stage = [&](int buf, int kstep) {
        const int kpos = kstep * BK;
#pragma unroll
        for (int i = 0; i < 2; ++i) {
            int c = i * 256 + tid;
            int r = c >> 2;
            int q = (c & 3) ^ ((r >> 1) & 3);
            gload_lds16(&A[(size_t)(bm + r) * K + kbase + kpos + q * 8],
                        &As[buf][(size_t)(i * 256 + wave * 64) * 8]);
            gload_lds16(&W[(size_t)(bn + r) * K + kbase + kpos + q * 8],
                        &Ws[buf][(size_t)(i * 256 + wave * 64) * 8]);
        }
    };

    auto compute = [&](int buf) {
        bf16x8 af[4], wf[4];
#pragma unroll
        for (int t = 0; t < 4; ++t) {
            af[t] = *(const bf16x8*)&As[buf][(wm + t * 16 + lr) * BK + kssw];
            wf[t] = *(const bf16x8*)&Ws[buf][(wn + t * 16 + lr) * BK + kssw];
        }
        __builtin_amdgcn_s_setprio(1);
#pragma unroll
        for (int mt = 0; mt < 4; ++mt)
#pragma unroll
            for (int nt = 0; nt < 4; ++nt)
                acc[mt][nt] = __builtin_amdgcn_mfma_f32_16x16x32_bf16(
                    af[mt], wf[nt], acc[mt][nt], 0, 0, 0);
        __builtin_amdgcn_s_setprio(0);
    };

    const int NKs = Ks >> 5;                  // 32-wide K-steps (144)

    stage(0, 0);
#pragma unroll 1
    for (int s = 0; s < NKs; s += 2) {
        __syncthreads();
        if (s + 1 < NKs) stage(1, s + 1);
        compute(0);
        __syncthreads();
        if (s + 2 < NKs) stage(0, s + 2);
        compute(1);
    }

    // C/D layout: col = lane&15, row = (lane>>4)*4 + reg
    float* Cz = Cout + (size_t)zt * M * N;
    const int col = lane & 15;
    const int rquad = (lane >> 4) * 4;
#pragma unroll
    for (int mt = 0; mt < 4; ++mt) {
#pragma unroll
        for (int nt = 0; nt < 4; ++nt) {
            int n = bn + wn + nt * 16 + col;
#pragma unroll
            for (int rg = 0; rg < 4; ++rg) {
                int m = bm + wm + mt * 16 + rquad + rg;
                Cz[(size_t)m * N + n] = acc[mt][nt][rg];
            }
        }
    }
}

// ----------------- 128x128 MFMA GEMM (dense epilogue) ----------------------
__global__ __launch_bounds__(256) void gemm_dense(
    const __bf16* __restrict__ A, const __bf16* __restrict__ W,
    float* __restrict__ Cout, const float* __restrict__ bias,
    int M, int N, int K) {
    constexpr int BK = 32;
    __shared__ __bf16 As[2][128 * BK];
    __shared__ __bf16 Ws[2][128 * BK];

    const int tid  = threadIdx.x;
    const int lane = tid & 63;
    const int wave = tid >> 6;

    const int id    = blockIdx.y * gridDim.x + blockIdx.x;
    const int mslab = gridDim.y >> 3;
    const int xcd   = id & 7;
    const int local = id >> 3;
    const int m_off = local % mslab;
    const int ntile = local / mslab;
    const int bm    = (xcd * mslab + m_off) * 128;
    const int bn    = ntile * 128;

    const int wm = (wave >> 1) * 64;
    const int wn = (wave & 1) * 64;
    const int lr = lane & 15;
    const int kq = lane >> 4;
    const int kssw = (kq ^ ((lr >> 1) & 3)) * 8;

    floatx4 acc[4][4] = {};

    auto stage = [&](int buf, int kpos) {
#pragma unroll
        for (int i = 0; i < 2; ++i) {
            int c = i * 256 + tid;
            int r = c >> 2;
            int q = (c & 3) ^ ((r >> 1) & 3);
            gload_lds16(&A[(size_t)(bm + r) * K + kpos + q * 8],
                        &As[buf][(size_t)(i * 256 + wave * 64) * 8]);
            gload_lds16(&W[(size_t)(bn + r) * K + kpos + q * 8],
                        &Ws[buf][(size_t)(i * 256 + wave * 64) * 8]);
        }
    };

    auto compute = [&](int buf) {
        bf16x8 af[4], wf[4];
#pragma unroll
        for (int t = 0; t < 4; ++t) {
            af[t] = *(const bf16x8*)&As[buf][(wm + t * 16 + lr) * BK + kssw];
            wf[t] = *(const bf16x8*)&Ws[buf][(wn + t * 16 + lr) * BK + kssw];
        }
#pragma unroll
        for (int mt = 0; mt < 4; ++mt)
#pragma unroll
            for (int nt = 0; nt < 4; ++nt)
                acc[mt][nt] = __builtin_amdgcn_mfma_f32_16x16x32_bf16(
                    af[mt], wf[nt], acc[mt][nt], 0, 0, 0);
    };

    stage(0, 0);
    for (int k0 = 0; k0 < K; k0 += 2 * BK) {
        __syncthreads();
        if (k0 + BK < K) stage(1, k0 + BK);
        compute(0);
        __syncthreads();
        if (k0 + 2 * BK < K) stage(0, k0 + 2 * BK);
        compute(1);
    }

    const int col = lane & 15;
    const int rquad = (lane >> 4) * 4;
#pragma unroll
    for (int mt = 0; mt < 4; ++mt) {
#pragma unroll
        for (int nt = 0; nt < 4; ++nt) {
            int n = bn + wn + nt * 16 + col;
#pragma unroll
            for (int rg = 0; rg < 4; ++rg) {
                int m = bm + wm + mt * 16 + rquad + rg;
                Cout[(size_t)m * N + n] = acc[mt][nt][rg] + bias[n];
            }
        }
    }
}

// ---------------------------------------------------------------------------
extern "C" void kernel_launch(void* const* d_in, const int* in_sizes, int n_in,
                              void* d_out, int out_size, void* d_ws, size_t ws_size,
                              hipStream_t stream) {
    const float* x   = (const float*)d_in[0];
    const float* bw0 = (const float*)d_in[1];
    const float* sw0 = (const float*)d_in[2];
    const float* ss0 = (const float*)d_in[3];
    const float* bw1 = (const float*)d_in[4];
    const float* sw1 = (const float*)d_in[5];
    const float* ss1 = (const float*)d_in[6];
    const float* dw  = (const float*)d_in[7];
    const float* db  = (const float*)d_in[8];
    float* out = (float*)d_out;

    char* ws = (char*)d_ws;
    __bf16* A0  = (__bf16*)(ws + OFF_A0);
    __bf16* W0  = (__bf16*)(ws + OFF_W0);
    __bf16* A1  = (__bf16*)(ws + OFF_A1);
    float*  P0  = (float*)(ws + OFF_P0);
    __bf16* W1  = (__bf16*)(ws + OFF_W1);
    float*  P1  = (float*)(ws + OFF_P1);
    __bf16* h1r = (__bf16*)(ws + OFF_H1R);
    __bf16* dwb = (__bf16*)(ws + OFF_DW);

    // Layer 0: K = 9216, splitK=2 -> grid 16x32x2 = 1024 blocks (4/CU)
    kan_wprep<<<(H0N * DIN) / 256, 256, 0, stream>>>(bw0, sw0, ss0, W0);
    kan_act<<<(BATCH * DIN) / 256, 256, 0, stream>>>(x, A0);
    gemm_t128<<<dim3(H0N / 128, BATCH / 128, 2), 256, 0, stream>>>(
        A0, W0, P0, BATCH, H0N, DIN * 9, DIN * 9 / 2);

    // Layer 1: K = 18432, splitK=4 -> grid 8x32x4 = 1024 blocks (4/CU)
    kan_wprep<<<(H1N * H0N) / 256, 256, 0, stream>>>(bw1, sw1, ss1, W1);
    kan_act_sum2<<<(BATCH * H0N) / 256, 256, 0, stream>>>(
        P0, P0 + (size_t)BATCH * H0N, A1);
    gemm_t128<<<dim3(H1N / 128, BATCH / 128, 4), 256, 0, stream>>>(
        A1, W1, P1, BATCH, H1N, H0N * 9, H0N * 9 / 4);

    // relu(sum of 4 partials) -> bf16
    relu_sum4<<<(BATCH * H1N / 4) / 256, 256, 0, stream>>>(
        P1, (size_t)BATCH * H1N, h1r, BATCH * H1N / 4);

    // Dense: out = h1r @ dw^T + db  (K = 1024)
    f2bf<<<(LOUT * H1N) / 256, 256, 0, stream>>>(dw, dwb, LOUT * H1N);
    gemm_dense<<<dim3(LOUT / 128, BATCH / 128), 256, 0, stream>>>(
        h1r, dwb, out, db, BATCH, LOUT, H1N);
}

// Round 6
// 649.262 us; speedup vs baseline: 1.0103x; 1.0032x over previous
//
#include <hip/hip_runtime.h>
#include <cstdint>
#include <cstddef>

// ---------------------------------------------------------------------------
// KAN encode: x(4096,1024) -> KANLinear(1024->2048) -> KANLinear(2048->1024)
//             -> ReLU -> Dense(1024->512)+bias
// bf16 MFMA GEMMs over augmented K (9 channels per input feature).
// R13: R12's merge raced on the workspace: OFF_DW lies INSIDE W1's range
//      (dwb overlay is only legal after gemm L1 consumes W1), and prep_all
//      wrote both concurrently -> absmax 7.7. Fix: merge only the three
//      disjoint prep ops (wprep0|act0|wprep1) into prep_all; fold f2bf into
//      relu_sum4 (both ordered after gemm L1, where W1 is dead).
//      GEMMs untouched (R9's proven gemm_pipe). 9 dispatches -> 6.
// ---------------------------------------------------------------------------

typedef __bf16 bf16x8 __attribute__((ext_vector_type(8)));
typedef float floatx4 __attribute__((ext_vector_type(4)));

#define BATCH 4096
#define DIN   1024
#define H0N   2048
#define H1N   1024
#define LOUT  512

// Workspace layout (bytes).
// Aliasing timeline (stream-ordered):
//   prep_all:  writes A0 [0,75.5M), W0 [75.5M,113.2M), W1 [218.1M,255.9M)
//   gemm L0:   reads A0,W0 -> writes P0 [151M,218.1M)
//   act_sum2:  reads P0 -> writes A1 [0,151M)        (A0,W0 dead)
//   gemm L1:   reads A1,W1 -> writes P1 [151M,218.1M) (P0 dead)
//   relu_f2bf: reads P1,dw -> writes h1r [218.1M,226.5M), dwb [226.5M,227.5M)
//              (W1 dead -> overlay legal ONLY here)
//   gemm_dense: reads h1r,dwb -> out
#define OFF_A0  ((size_t)0)           // bf16 4096*9216  = 75,497,472
#define OFF_W0  ((size_t)75497472)    // bf16 2048*9216  = 37,748,736
#define OFF_A1  ((size_t)0)           // bf16 4096*18432 = 150,994,944 (overlays A0+W0)
#define OFF_P0  ((size_t)150994944)   // f32 2*4096*2048 = 67,108,864
#define OFF_W1  ((size_t)218103808)   // bf16 1024*18432 = 37,748,736
#define OFF_P1  ((size_t)150994944)   // f32 4*4096*1024 = 67,108,864 (overlays P0)
#define OFF_H1R ((size_t)218103808)   // bf16 4096*1024  =  8,388,608 (overlays W1)
#define OFF_DW  ((size_t)226492416)   // bf16 512*1024   =  1,048,576 (overlays W1)

// --------------------------- spline bases ----------------------------------
__device__ __forceinline__ void bspline8(float x, float* out) {
    float b[11];
#pragma unroll
    for (int j = 0; j < 11; ++j) {
        float t0 = (j - 3) * 0.4f - 1.0f;
        float t1 = (j - 2) * 0.4f - 1.0f;
        b[j] = (x >= t0 && x < t1) ? 1.0f : 0.0f;
    }
#pragma unroll
    for (int k = 1; k <= 3; ++k) {
#pragma unroll
        for (int j = 0; j + k < 11; ++j) {
            float tj   = (j - 3) * 0.4f - 1.0f;
            float tj1  = (j - 2) * 0.4f - 1.0f;
            float tjk  = (j + k - 3) * 0.4f - 1.0f;
            float tjk1 = (j + k - 2) * 0.4f - 1.0f;
            float left  = (x - tj)   * (1.0f / (tjk - tj));
            float right = (tjk1 - x) * (1.0f / (tjk1 - tj1));
            b[j] = left * b[j] + right * b[j + 1];
        }
    }
#pragma unroll
    for (int j = 0; j < 8; ++j) out[j] = b[j];
}

// Store 256 threads * 9 bf16 via LDS as 288 coalesced 16B chunks.
// Loop-safe: trailing __syncthreads guards WAR on sbuf reuse.
__device__ __forceinline__ void coalesced_store9(__bf16* block_dst, const __bf16* vals) {
    __shared__ __bf16 sbuf[256 * 9];
    __bf16* p = &sbuf[threadIdx.x * 9];
#pragma unroll
    for (int j = 0; j < 9; ++j) p[j] = vals[j];
    __syncthreads();
    const uint4* src = (const uint4*)sbuf;
    uint4* dst = (uint4*)block_dst;
    dst[threadIdx.x] = src[threadIdx.x];
    if (threadIdx.x < 32) dst[256 + threadIdx.x] = src[256 + threadIdx.x];
    __syncthreads();
}

__device__ __forceinline__ void act9(float v, __bf16* r) {
    float s = v / (1.0f + __expf(-v));
    float bb[8];
    bspline8(v, bb);
    r[0] = (__bf16)s;
#pragma unroll
    for (int j = 0; j < 8; ++j) r[1 + j] = (__bf16)bb[j];
}

__device__ __forceinline__ void act_unit(const float* __restrict__ in,
                                         __bf16* __restrict__ out, int u) {
    int base = u * 256;
    float v = in[base + threadIdx.x];
    __bf16 r[9];
    act9(v, r);
    coalesced_store9(out + (size_t)base * 9, r);
}

__device__ __forceinline__ void wprep_unit(const float* __restrict__ bw,
                                           const float* __restrict__ sw,
                                           const float* __restrict__ ss,
                                           __bf16* __restrict__ out, int u) {
    int base = u * 256;
    int idx = base + threadIdx.x;
    float b  = bw[idx];
    float sc = ss[idx];
    const float4* sv = (const float4*)(sw + (size_t)idx * 8);
    float4 a = sv[0], c = sv[1];
    __bf16 r[9];
    r[0] = (__bf16)b;
    r[1] = (__bf16)(a.x * sc); r[2] = (__bf16)(a.y * sc);
    r[3] = (__bf16)(a.z * sc); r[4] = (__bf16)(a.w * sc);
    r[5] = (__bf16)(c.x * sc); r[6] = (__bf16)(c.y * sc);
    r[7] = (__bf16)(c.z * sc); r[8] = (__bf16)(c.w * sc);
    coalesced_store9(out + (size_t)base * 9, r);
}

// ---- merged prep: wprep0 | act0 | wprep1 (DISJOINT regions only) ----------
#define U_W0   (H0N * DIN / 256)            // 8192
#define U_ACT  (BATCH * DIN / 256)          // 16384
#define U_W1   (H1N * H0N / 256)            // 8192
#define U_TOT  (U_W0 + U_ACT + U_W1)        // 32768

__global__ void prep_all(const float* __restrict__ x, __bf16* __restrict__ A0,
                         const float* __restrict__ bw0, const float* __restrict__ sw0,
                         const float* __restrict__ ss0, __bf16* __restrict__ W0,
                         const float* __restrict__ bw1, const float* __restrict__ sw1,
                         const float* __restrict__ ss1, __bf16* __restrict__ W1) {
#pragma unroll 1
    for (int u = blockIdx.x; u < U_TOT; u += gridDim.x) {
        if (u < U_W0) {
            wprep_unit(bw0, sw0, ss0, W0, u);
        } else if (u < U_W0 + U_ACT) {
            act_unit(x, A0, u - U_W0);
        } else {
            wprep_unit(bw1, sw1, ss1, W1, u - (U_W0 + U_ACT));
        }
    }
}

// ---- act_sum2: persistent grid-stride over 32768 units ---------------------
__global__ void kan_act_sum2(const float* __restrict__ pa, const float* __restrict__ pb,
                             __bf16* __restrict__ out) {
    const int UNITS = BATCH * H0N / 256;    // 32768
#pragma unroll 1
    for (int u = blockIdx.x; u < UNITS; u += gridDim.x) {
        int idx = u * 256 + threadIdx.x;
        float v = pa[idx] + pb[idx];
        __bf16 r[9];
        act9(v, r);
        coalesced_store9(out + (size_t)u * 256 * 9, r);
    }
}

// ---- relu_sum4 + f2bf (both ordered after gemm L1; W1 dead) ---------------
__global__ void relu_f2bf(const float* __restrict__ p, size_t stride,
                          __bf16* __restrict__ out, int total4,
                          const float* __restrict__ dwf, __bf16* __restrict__ dwb,
                          int dwtotal4) {
#pragma unroll 1
    for (int idx = blockIdx.x * 256 + threadIdx.x; idx < total4;
         idx += gridDim.x * 256) {
        const float4* p0 = (const float4*)p;
        const float4* p1 = (const float4*)(p + stride);
        const float4* p2 = (const float4*)(p + 2 * stride);
        const float4* p3 = (const float4*)(p + 3 * stride);
        float4 a = p0[idx], b = p1[idx], c = p2[idx], d = p3[idx];
        __bf16 r[4];
        r[0] = (__bf16)fmaxf(a.x + b.x + c.x + d.x, 0.0f);
        r[1] = (__bf16)fmaxf(a.y + b.y + c.y + d.y, 0.0f);
        r[2] = (__bf16)fmaxf(a.z + b.z + c.z + d.z, 0.0f);
        r[3] = (__bf16)fmaxf(a.w + b.w + c.w + d.w, 0.0f);
        *(uint2*)&out[(size_t)idx * 4] = *(uint2*)r;
    }
#pragma unroll 1
    for (int idx = blockIdx.x * 256 + threadIdx.x; idx < dwtotal4;
         idx += gridDim.x * 256) {
        float4 a = ((const float4*)dwf)[idx];
        __bf16 r[4];
        r[0] = (__bf16)a.x; r[1] = (__bf16)a.y;
        r[2] = (__bf16)a.z; r[3] = (__bf16)a.w;
        *(uint2*)&dwb[(size_t)idx * 4] = *(uint2*)r;
    }
}

// --------------------------- staging helper --------------------------------
__device__ __forceinline__ void gload_lds16(const void* g, void* l) {
    __builtin_amdgcn_global_load_lds(
        (const __attribute__((address_space(1))) uint32_t*)g,
        (__attribute__((address_space(3))) uint32_t*)l, 16, 0, 0);
}

// Bank swizzle: LDS slot (row r, pos p) holds global chunk q = p ^ ((r>>1)&3).
// Frag reads (rows base+lr, lr=0..15, chunk kq) land 2 lanes per 4-bank group
// -> 2-way aliasing = free (verified: SQ_LDS_BANK_CONFLICT == 0).

// ---- pipelined MFMA GEMM: 256x128 tile, 4 waves (64x128 each), 2 blk/CU ---
// C(M,N) = A(M,K) @ W(N,K)^T, bf16 in, fp32 out (split-K partial per z).
// 3-deep cyclic LDS; per K-step: {stage slab s+2 | reads(s) | 32 MFMA |
// s_waitcnt vmcnt(6) lgkmcnt(0) | s_barrier}. vmcnt never drains to 0 in
// the main loop (6 loads = next stage stay in flight across the barrier).
__global__ __launch_bounds__(256, 2) void gemm_pipe(
    const __bf16* __restrict__ A, const __bf16* __restrict__ W,
    float* __restrict__ Cout, int M, int N, int K, int Ks) {
    constexpr int BK = 32;                    // 64 B LDS rows (4 x 16B chunks)
    __shared__ __bf16 As[3][256 * BK];        // 3 x 16 KB
    __shared__ __bf16 Ws[3][128 * BK];        // 3 x 8 KB

    const int tid  = threadIdx.x;
    const int lane = tid & 63;
    const int wave = tid >> 6;

    // XCD-aware swizzle (round-robin dispatch: id&7 = XCD)
    const int id    = (blockIdx.z * gridDim.y + blockIdx.y) * gridDim.x + blockIdx.x;
    const int mslab = gridDim.y >> 3;
    const int xcd   = id & 7;
    const int local = id >> 3;
    const int m_off = local % mslab;
    const int rest  = local / mslab;
    const int ntile = rest % gridDim.x;
    const int zt    = rest / gridDim.x;
    const int bm    = (xcd * mslab + m_off) * 256;
    const int bn    = ntile * 128;
    const int kbase = zt * Ks;

    const int wm = wave * 64;
    const int lr = lane & 15;
    const int kq = lane >> 4;                      // k-chunk 0..3
    const int kssw = (kq ^ ((lr >> 1) & 3)) * 8;   // swizzled frag chunk offset

    floatx4 acc[4][8] = {};

    auto stage = [&](int slot, int kstep) {
        const int kpos = kstep * BK;
#pragma unroll
        for (int i = 0; i < 4; ++i) {          // A: 1024 chunks of 16 B
            int c = i * 256 + tid;
            int r = c >> 2;
            int q = (c & 3) ^ ((r >> 1) & 3);  // swizzled source chunk
            gload_lds16(&A[(size_t)(bm + r) * K + kbase + kpos + q * 8],
                        &As[slot][(size_t)(i * 256 + wave * 64) * 8]);
        }
#pragma unroll
        for (int i = 0; i < 2; ++i) {          // W: 512 chunks
            int c = i * 256 + tid;
            int r = c >> 2;
            int q = (c & 3) ^ ((r >> 1) & 3);
            gload_lds16(&W[(size_t)(bn + r) * K + kbase + kpos + q * 8],
                        &Ws[slot][(size_t)(i * 256 + wave * 64) * 8]);
        }
    };

    auto compute = [&](int slot) {
        bf16x8 af[4], wf[8];
#pragma unroll
        for (int t = 0; t < 4; ++t)
            af[t] = *(const bf16x8*)&As[slot][(wm + t * 16 + lr) * BK + kssw];
#pragma unroll
        for (int t = 0; t < 8; ++t)
            wf[t] = *(const bf16x8*)&Ws[slot][(t * 16 + lr) * BK + kssw];
        __builtin_amdgcn_s_setprio(1);
#pragma unroll
        for (int mt = 0; mt < 4; ++mt)
#pragma unroll
            for (int nt = 0; nt < 8; ++nt)
                acc[mt][nt] = __builtin_amdgcn_mfma_f32_16x16x32_bf16(
                    af[mt], wf[nt], acc[mt][nt], 0, 0, 0);
        __builtin_amdgcn_s_setprio(0);
    };

    const int NKs = Ks >> 5;                  // 32-wide K-steps (144)

    // Prologue: stage slabs 0,1 (12 loads/wave); need slab 0 -> vmcnt(6).
    stage(0, 0);
    stage(1, 1);
    asm volatile("s_waitcnt vmcnt(6)" ::: "memory");
    __builtin_amdgcn_s_barrier();

    int sl = 0;
#pragma unroll 1
    for (int s = 0; s < NKs - 2; ++s) {
        int sln = sl + 2; if (sln >= 3) sln -= 3;
        stage(sln, s + 2);                    // DMA issues first, hides under compute
        compute(sl);
        // slab s+1 must be landed; stage(s+2)'s 6 loads stay in flight.
        asm volatile("s_waitcnt vmcnt(6) lgkmcnt(0)" ::: "memory");
        __builtin_amdgcn_s_barrier();
        sl = (sl == 2) ? 0 : sl + 1;
    }
    compute(sl);
    asm volatile("s_waitcnt vmcnt(0) lgkmcnt(0)" ::: "memory");
    __builtin_amdgcn_s_barrier();
    sl = (sl == 2) ? 0 : sl + 1;
    compute(sl);

    // C/D layout: col = lane&15, row = (lane>>4)*4 + reg
    float* Cz = Cout + (size_t)zt * M * N;
    const int col = lane & 15;
    const int rquad = (lane >> 4) * 4;
#pragma unroll
    for (int mt = 0; mt < 4; ++mt) {
#pragma unroll
        for (int nt = 0; nt < 8; ++nt) {
            int n = bn + nt * 16 + col;
#pragma unroll
            for (int rg = 0; rg < 4; ++rg) {
                int m = bm + wm + mt * 16 + rquad + rg;
                Cz[(size_t)m * N + n] = acc[mt][nt][rg];
            }
        }
    }
}

// ----------------- 128x128 MFMA GEMM (dense epilogue) ----------------------
__global__ __launch_bounds__(256) void gemm_dense(
    const __bf16* __restrict__ A, const __bf16* __restrict__ W,
    float* __restrict__ Cout, const float* __restrict__ bias,
    int M, int N, int K) {
    constexpr int BK = 32;
    __shared__ __bf16 As[2][128 * BK];
    __shared__ __bf16 Ws[2][128 * BK];

    const int tid  = threadIdx.x;
    const int lane = tid & 63;
    const int wave = tid >> 6;

    const int id    = blockIdx.y * gridDim.x + blockIdx.x;
    const int mslab = gridDim.y >> 3;
    const int xcd   = id & 7;
    const int local = id >> 3;
    const int m_off = local % mslab;
    const int ntile = local / mslab;
    const int bm    = (xcd * mslab + m_off) * 128;
    const int bn    = ntile * 128;

    const int wm = (wave >> 1) * 64;
    const int wn = (wave & 1) * 64;
    const int lr = lane & 15;
    const int kq = lane >> 4;
    const int kssw = (kq ^ ((lr >> 1) & 3)) * 8;

    floatx4 acc[4][4] = {};

    auto stage = [&](int buf, int kpos) {
#pragma unroll
        for (int i = 0; i < 2; ++i) {
            int c = i * 256 + tid;
            int r = c >> 2;
            int q = (c & 3) ^ ((r >> 1) & 3);
            gload_lds16(&A[(size_t)(bm + r) * K + kpos + q * 8],
                        &As[buf][(size_t)(i * 256 + wave * 64) * 8]);
            gload_lds16(&W[(size_t)(bn + r) * K + kpos + q * 8],
                        &Ws[buf][(size_t)(i * 256 + wave * 64) * 8]);
        }
    };

    auto compute = [&](int buf) {
        bf16x8 af[4], wf[4];
#pragma unroll
        for (int t = 0; t < 4; ++t) {
            af[t] = *(const bf16x8*)&As[buf][(wm + t * 16 + lr) * BK + kssw];
            wf[t] = *(const bf16x8*)&Ws[buf][(wn + t * 16 + lr) * BK + kssw];
        }
#pragma unroll
        for (int mt = 0; mt < 4; ++mt)
#pragma unroll
            for (int nt = 0; nt < 4; ++nt)
                acc[mt][nt] = __builtin_amdgcn_mfma_f32_16x16x32_bf16(
                    af[mt], wf[nt], acc[mt][nt], 0, 0, 0);
    };

    stage(0, 0);
    for (int k0 = 0; k0 < K; k0 += 2 * BK) {
        __syncthreads();
        if (k0 + BK < K) stage(1, k0 + BK);
        compute(0);
        __syncthreads();
        if (k0 + 2 * BK < K) stage(0, k0 + 2 * BK);
        compute(1);
    }

    const int col = lane & 15;
    const int rquad = (lane >> 4) * 4;
#pragma unroll
    for (int mt = 0; mt < 4; ++mt) {
#pragma unroll
        for (int nt = 0; nt < 4; ++nt) {
            int n = bn + wn + nt * 16 + col;
#pragma unroll
            for (int rg = 0; rg < 4; ++rg) {
                int m = bm + wm + mt * 16 + rquad + rg;
                Cout[(size_t)m * N + n] = acc[mt][nt][rg] + bias[n];
            }
        }
    }
}

// ---------------------------------------------------------------------------
extern "C" void kernel_launch(void* const* d_in, const int* in_sizes, int n_in,
                              void* d_out, int out_size, void* d_ws, size_t ws_size,
                              hipStream_t stream) {
    const float* x   = (const float*)d_in[0];
    const float* bw0 = (const float*)d_in[1];
    const float* sw0 = (const float*)d_in[2];
    const float* ss0 = (const float*)d_in[3];
    const float* bw1 = (const float*)d_in[4];
    const float* sw1 = (const float*)d_in[5];
    const float* ss1 = (const float*)d_in[6];
    const float* dw  = (const float*)d_in[7];
    const float* db  = (const float*)d_in[8];
    float* out = (float*)d_out;

    char* ws = (char*)d_ws;
    __bf16* A0  = (__bf16*)(ws + OFF_A0);
    __bf16* W0  = (__bf16*)(ws + OFF_W0);
    __bf16* A1  = (__bf16*)(ws + OFF_A1);
    float*  P0  = (float*)(ws + OFF_P0);
    __bf16* W1  = (__bf16*)(ws + OFF_W1);
    float*  P1  = (float*)(ws + OFF_P1);
    __bf16* h1r = (__bf16*)(ws + OFF_H1R);
    __bf16* dwb = (__bf16*)(ws + OFF_DW);

    // Disjoint-region prep in one persistent launch (wprep0|act0|wprep1)
    prep_all<<<2048, 256, 0, stream>>>(x, A0, bw0, sw0, ss0, W0,
                                       bw1, sw1, ss1, W1);

    // Layer 0: K = 9216, splitK=2 -> grid 16x16x2 = 512 blocks (2/CU)
    gemm_pipe<<<dim3(H0N / 128, BATCH / 256, 2), 256, 0, stream>>>(
        A0, W0, P0, BATCH, H0N, DIN * 9, DIN * 9 / 2);

    // act(sum of 2 partials) -> augmented A1
    kan_act_sum2<<<2048, 256, 0, stream>>>(
        P0, P0 + (size_t)BATCH * H0N, A1);

    // Layer 1: K = 18432, splitK=4 -> grid 8x16x4 = 512 blocks (2/CU)
    gemm_pipe<<<dim3(H1N / 128, BATCH / 256, 4), 256, 0, stream>>>(
        A1, W1, P1, BATCH, H1N, H0N * 9, H0N * 9 / 4);

    // relu(sum of 4 partials) -> bf16, plus dw -> bf16 (W1 dead here)
    relu_f2bf<<<2048, 256, 0, stream>>>(
        P1, (size_t)BATCH * H1N, h1r, BATCH * H1N / 4,
        dw, dwb, LOUT * H1N / 4);

    // Dense: out = h1r @ dw^T + db  (K = 1024)
    gemm_dense<<<dim3(LOUT / 128, BATCH / 128), 256, 0, stream>>>(
        h1r, dwb, out, db, BATCH, LOUT, H1N);
}

// Round 7
// 597.726 us; speedup vs baseline: 1.0974x; 1.0862x over previous
//
#include <hip/hip_runtime.h>
#include <cstdint>
#include <cstddef>

// ---------------------------------------------------------------------------
// KAN encode: x(4096,1024) -> KANLinear(1024->2048) -> KANLinear(2048->1024)
//             -> ReLU -> Dense(1024->512)+bias
// bf16 MFMA GEMMs over augmented K (9 channels per input feature).
// R14: R13's persistent merged prep regressed (+35 us: per-iteration
//      __syncthreads vmcnt(0) drains serialize the LDS-coalesced stores).
//      Full revert to R2-exact structure (proven 614.5 us). ONE change:
//      split-K partials P0/P1 stored as bf16 instead of f32 (-134 MB
//      intermediate traffic). Partials are pure intermediates (summed in
//      f32 then act9/relu); bf16 rounding on |p|~2 adds ~6e-3 to h0,
//      final absmax ~0.05 << 0.156 threshold.
// ---------------------------------------------------------------------------

typedef __bf16 bf16x8 __attribute__((ext_vector_type(8)));
typedef __bf16 bf16x4v __attribute__((ext_vector_type(4)));
typedef float floatx4 __attribute__((ext_vector_type(4)));

#define BATCH 4096
#define DIN   1024
#define H0N   2048
#define H1N   1024
#define LOUT  512

// Workspace layout (bytes). Total = 227,540,992 (unchanged envelope).
// P0/P1 now bf16: occupy first half of their old f32 regions.
#define OFF_A0  ((size_t)0)           // bf16 4096*9216  = 75,497,472
#define OFF_W0  ((size_t)75497472)    // bf16 2048*9216  = 37,748,736
#define OFF_A1  ((size_t)0)           // bf16 4096*18432 = 150,994,944 (overlays A0+W0)
#define OFF_P0  ((size_t)150994944)   // bf16 2*4096*2048 = 33,554,432
#define OFF_W1  ((size_t)218103808)   // bf16 1024*18432 = 37,748,736
#define OFF_P1  ((size_t)150994944)   // bf16 4*4096*1024 = 33,554,432 (overlays P0)
#define OFF_H1R ((size_t)218103808)   // bf16 4096*1024  =  8,388,608 (overlays W1)
#define OFF_DW  ((size_t)226492416)   // bf16 512*1024   =  1,048,576

// --------------------------- spline bases ----------------------------------
__device__ __forceinline__ void bspline8(float x, float* out) {
    float b[11];
#pragma unroll
    for (int j = 0; j < 11; ++j) {
        float t0 = (j - 3) * 0.4f - 1.0f;
        float t1 = (j - 2) * 0.4f - 1.0f;
        b[j] = (x >= t0 && x < t1) ? 1.0f : 0.0f;
    }
#pragma unroll
    for (int k = 1; k <= 3; ++k) {
#pragma unroll
        for (int j = 0; j + k < 11; ++j) {
            float tj   = (j - 3) * 0.4f - 1.0f;
            float tj1  = (j - 2) * 0.4f - 1.0f;
            float tjk  = (j + k - 3) * 0.4f - 1.0f;
            float tjk1 = (j + k - 2) * 0.4f - 1.0f;
            float left  = (x - tj)   * (1.0f / (tjk - tj));
            float right = (tjk1 - x) * (1.0f / (tjk1 - tj1));
            b[j] = left * b[j] + right * b[j + 1];
        }
    }
#pragma unroll
    for (int j = 0; j < 8; ++j) out[j] = b[j];
}

// Store 256 threads * 9 bf16 via LDS as 288 coalesced 16B chunks.
__device__ __forceinline__ void coalesced_store9(__bf16* block_dst, const __bf16* vals) {
    __shared__ __bf16 sbuf[256 * 9];
    __bf16* p = &sbuf[threadIdx.x * 9];
#pragma unroll
    for (int j = 0; j < 9; ++j) p[j] = vals[j];
    __syncthreads();
    const uint4* src = (const uint4*)sbuf;
    uint4* dst = (uint4*)block_dst;
    dst[threadIdx.x] = src[threadIdx.x];
    if (threadIdx.x < 32) dst[256 + threadIdx.x] = src[256 + threadIdx.x];
}

__device__ __forceinline__ void act9(float v, __bf16* r) {
    float s = v / (1.0f + __expf(-v));
    float bb[8];
    bspline8(v, bb);
    r[0] = (__bf16)s;
#pragma unroll
    for (int j = 0; j < 8; ++j) r[1 + j] = (__bf16)bb[j];
}

__global__ void kan_act(const float* __restrict__ in, __bf16* __restrict__ out) {
    int base = blockIdx.x * 256;
    float v = in[base + threadIdx.x];
    __bf16 r[9];
    act9(v, r);
    coalesced_store9(out + (size_t)base * 9, r);
}

// partials are bf16 now; sum in f32
__global__ void kan_act_sum2(const __bf16* __restrict__ pa, const __bf16* __restrict__ pb,
                             __bf16* __restrict__ out) {
    int base = blockIdx.x * 256;
    int idx = base + threadIdx.x;
    float v = (float)pa[idx] + (float)pb[idx];
    __bf16 r[9];
    act9(v, r);
    coalesced_store9(out + (size_t)base * 9, r);
}

__global__ void relu_sum4(const __bf16* __restrict__ p, size_t stride,
                          __bf16* __restrict__ out, int total4) {
    int idx = blockIdx.x * 256 + threadIdx.x;
    if (idx >= total4) return;
    const bf16x4v* p0 = (const bf16x4v*)p;
    const bf16x4v* p1 = (const bf16x4v*)(p + stride);
    const bf16x4v* p2 = (const bf16x4v*)(p + 2 * stride);
    const bf16x4v* p3 = (const bf16x4v*)(p + 3 * stride);
    bf16x4v a = p0[idx], b = p1[idx], c = p2[idx], d = p3[idx];
    __bf16 r[4];
#pragma unroll
    for (int j = 0; j < 4; ++j) {
        float s = (float)a[j] + (float)b[j] + (float)c[j] + (float)d[j];
        r[j] = (__bf16)fmaxf(s, 0.0f);
    }
    *(uint2*)&out[(size_t)idx * 4] = *(uint2*)r;
}

__global__ void kan_wprep(const float* __restrict__ bw, const float* __restrict__ sw,
                          const float* __restrict__ ss, __bf16* __restrict__ out) {
    int base = blockIdx.x * 256;
    int idx = base + threadIdx.x;
    float b  = bw[idx];
    float sc = ss[idx];
    const float4* sv = (const float4*)(sw + (size_t)idx * 8);
    float4 a = sv[0], c = sv[1];
    __bf16 r[9];
    r[0] = (__bf16)b;
    r[1] = (__bf16)(a.x * sc); r[2] = (__bf16)(a.y * sc);
    r[3] = (__bf16)(a.z * sc); r[4] = (__bf16)(a.w * sc);
    r[5] = (__bf16)(c.x * sc); r[6] = (__bf16)(c.y * sc);
    r[7] = (__bf16)(c.z * sc); r[8] = (__bf16)(c.w * sc);
    coalesced_store9(out + (size_t)base * 9, r);
}

__global__ void f2bf(const float* __restrict__ in, __bf16* __restrict__ out,
                     int total) {
    int idx = blockIdx.x * 256 + threadIdx.x;
    if (idx < total) out[idx] = (__bf16)in[idx];
}

// --------------------------- staging helper --------------------------------
__device__ __forceinline__ void gload_lds16(const void* g, void* l) {
    __builtin_amdgcn_global_load_lds(
        (const __attribute__((address_space(1))) uint32_t*)g,
        (__attribute__((address_space(3))) uint32_t*)l, 16, 0, 0);
}

// Bank swizzle: LDS slot (row r, pos p) holds global chunk q = p ^ ((r>>1)&3).
// Frag reads (rows base+lr, lr=0..15, chunk kq) land 2 lanes per 4-bank group
// -> 2-way aliasing = free (verified: SQ_LDS_BANK_CONFLICT == 0).

// ---- pipelined MFMA GEMM: 256x128 tile, 4 waves (64x128 each), 2 blk/CU ---
// C(M,N) = A(M,K) @ W(N,K)^T, bf16 in, bf16 partial out (split-K per z).
// 3-deep cyclic LDS; per K-step: {stage slab s+2 | reads(s) | 32 MFMA |
// s_waitcnt vmcnt(6) lgkmcnt(0) | s_barrier}. vmcnt never drains to 0 in
// the main loop (6 loads = next stage stay in flight across the barrier).
__global__ __launch_bounds__(256, 2) void gemm_pipe(
    const __bf16* __restrict__ A, const __bf16* __restrict__ W,
    __bf16* __restrict__ Cout, int M, int N, int K, int Ks) {
    constexpr int BK = 32;                    // 64 B LDS rows (4 x 16B chunks)
    __shared__ __bf16 As[3][256 * BK];        // 3 x 16 KB
    __shared__ __bf16 Ws[3][128 * BK];        // 3 x 8 KB

    const int tid  = threadIdx.x;
    const int lane = tid & 63;
    const int wave = tid >> 6;

    // XCD-aware swizzle (round-robin dispatch: id&7 = XCD)
    const int id    = (blockIdx.z * gridDim.y + blockIdx.y) * gridDim.x + blockIdx.x;
    const int mslab = gridDim.y >> 3;
    const int xcd   = id & 7;
    const int local = id >> 3;
    const int m_off = local % mslab;
    const int rest  = local / mslab;
    const int ntile = rest % gridDim.x;
    const int zt    = rest / gridDim.x;
    const int bm    = (xcd * mslab + m_off) * 256;
    const int bn    = ntile * 128;
    const int kbase = zt * Ks;

    const int wm = wave * 64;
    const int lr = lane & 15;
    const int kq = lane >> 4;                      // k-chunk 0..3
    const int kssw = (kq ^ ((lr >> 1) & 3)) * 8;   // swizzled frag chunk offset

    floatx4 acc[4][8] = {};

    auto stage = [&](int slot, int kstep) {
        const int kpos = kstep * BK;
#pragma unroll
        for (int i = 0; i < 4; ++i) {          // A: 1024 chunks of 16 B
            int c = i * 256 + tid;
            int r = c >> 2;
            int q = (c & 3) ^ ((r >> 1) & 3);  // swizzled source chunk
            gload_lds16(&A[(size_t)(bm + r) * K + kbase + kpos + q * 8],
                        &As[slot][(size_t)(i * 256 + wave * 64) * 8]);
        }
#pragma unroll
        for (int i = 0; i < 2; ++i) {          // W: 512 chunks
            int c = i * 256 + tid;
            int r = c >> 2;
            int q = (c & 3) ^ ((r >> 1) & 3);
            gload_lds16(&W[(size_t)(bn + r) * K + kbase + kpos + q * 8],
                        &Ws[slot][(size_t)(i * 256 + wave * 64) * 8]);
        }
    };

    auto compute = [&](int slot) {
        bf16x8 af[4], wf[8];
#pragma unroll
        for (int t = 0; t < 4; ++t)
            af[t] = *(const bf16x8*)&As[slot][(wm + t * 16 + lr) * BK + kssw];
#pragma unroll
        for (int t = 0; t < 8; ++t)
            wf[t] = *(const bf16x8*)&Ws[slot][(t * 16 + lr) * BK + kssw];
        __builtin_amdgcn_s_setprio(1);
#pragma unroll
        for (int mt = 0; mt < 4; ++mt)
#pragma unroll
            for (int nt = 0; nt < 8; ++nt)
                acc[mt][nt] = __builtin_amdgcn_mfma_f32_16x16x32_bf16(
                    af[mt], wf[nt], acc[mt][nt], 0, 0, 0);
        __builtin_amdgcn_s_setprio(0);
    };

    const int NKs = Ks >> 5;                  // 32-wide K-steps (144)

    // Prologue: stage slabs 0,1 (12 loads/wave); need slab 0 -> vmcnt(6).
    stage(0, 0);
    stage(1, 1);
    asm volatile("s_waitcnt vmcnt(6)" ::: "memory");
    __builtin_amdgcn_s_barrier();

    int sl = 0;
#pragma unroll 1
    for (int s = 0; s < NKs - 2; ++s) {
        int sln = sl + 2; if (sln >= 3) sln -= 3;
        stage(sln, s + 2);                    // DMA issues first, hides under compute
        compute(sl);
        // slab s+1 must be landed; stage(s+2)'s 6 loads stay in flight.
        asm volatile("s_waitcnt vmcnt(6) lgkmcnt(0)" ::: "memory");
        __builtin_amdgcn_s_barrier();
        sl = (sl == 2) ? 0 : sl + 1;
    }
    compute(sl);
    asm volatile("s_waitcnt vmcnt(0) lgkmcnt(0)" ::: "memory");
    __builtin_amdgcn_s_barrier();
    sl = (sl == 2) ? 0 : sl + 1;
    compute(sl);

    // C/D layout: col = lane&15, row = (lane>>4)*4 + reg.  bf16 partial store.
    __bf16* Cz = Cout + (size_t)zt * M * N;
    const int col = lane & 15;
    const int rquad = (lane >> 4) * 4;
#pragma unroll
    for (int mt = 0; mt < 4; ++mt) {
#pragma unroll
        for (int nt = 0; nt < 8; ++nt) {
            int n = bn + nt * 16 + col;
#pragma unroll
            for (int rg = 0; rg < 4; ++rg) {
                int m = bm + wm + mt * 16 + rquad + rg;
                Cz[(size_t)m * N + n] = (__bf16)acc[mt][nt][rg];
            }
        }
    }
}

// ----------------- 128x128 MFMA GEMM (dense epilogue) ----------------------
__global__ __launch_bounds__(256) void gemm_dense(
    const __bf16* __restrict__ A, const __bf16* __restrict__ W,
    float* __restrict__ Cout, const float* __restrict__ bias,
    int M, int N, int K) {
    constexpr int BK = 32;
    __shared__ __bf16 As[2][128 * BK];
    __shared__ __bf16 Ws[2][128 * BK];

    const int tid  = threadIdx.x;
    const int lane = tid & 63;
    const int wave = tid >> 6;

    const int id    = blockIdx.y * gridDim.x + blockIdx.x;
    const int mslab = gridDim.y >> 3;
    const int xcd   = id & 7;
    const int local = id >> 3;
    const int m_off = local % mslab;
    const int ntile = local / mslab;
    const int bm    = (xcd * mslab + m_off) * 128;
    const int bn    = ntile * 128;

    const int wm = (wave >> 1) * 64;
    const int wn = (wave & 1) * 64;
    const int lr = lane & 15;
    const int kq = lane >> 4;
    const int kssw = (kq ^ ((lr >> 1) & 3)) * 8;

    floatx4 acc[4][4] = {};

    auto stage = [&](int buf, int kpos) {
#pragma unroll
        for (int i = 0; i < 2; ++i) {
            int c = i * 256 + tid;
            int r = c >> 2;
            int q = (c & 3) ^ ((r >> 1) & 3);
            gload_lds16(&A[(size_t)(bm + r) * K + kpos + q * 8],
                        &As[buf][(size_t)(i * 256 + wave * 64) * 8]);
            gload_lds16(&W[(size_t)(bn + r) * K + kpos + q * 8],
                        &Ws[buf][(size_t)(i * 256 + wave * 64) * 8]);
        }
    };

    auto compute = [&](int buf) {
        bf16x8 af[4], wf[4];
#pragma unroll
        for (int t = 0; t < 4; ++t) {
            af[t] = *(const bf16x8*)&As[buf][(wm + t * 16 + lr) * BK + kssw];
            wf[t] = *(const bf16x8*)&Ws[buf][(wn + t * 16 + lr) * BK + kssw];
        }
#pragma unroll
        for (int mt = 0; mt < 4; ++mt)
#pragma unroll
            for (int nt = 0; nt < 4; ++nt)
                acc[mt][nt] = __builtin_amdgcn_mfma_f32_16x16x32_bf16(
                    af[mt], wf[nt], acc[mt][nt], 0, 0, 0);
    };

    stage(0, 0);
    for (int k0 = 0; k0 < K; k0 += 2 * BK) {
        __syncthreads();
        if (k0 + BK < K) stage(1, k0 + BK);
        compute(0);
        __syncthreads();
        if (k0 + 2 * BK < K) stage(0, k0 + 2 * BK);
        compute(1);
    }

    const int col = lane & 15;
    const int rquad = (lane >> 4) * 4;
#pragma unroll
    for (int mt = 0; mt < 4; ++mt) {
#pragma unroll
        for (int nt = 0; nt < 4; ++nt) {
            int n = bn + wn + nt * 16 + col;
#pragma unroll
            for (int rg = 0; rg < 4; ++rg) {
                int m = bm + wm + mt * 16 + rquad + rg;
                Cout[(size_t)m * N + n] = acc[mt][nt][rg] + bias[n];
            }
        }
    }
}

// ---------------------------------------------------------------------------
extern "C" void kernel_launch(void* const* d_in, const int* in_sizes, int n_in,
                              void* d_out, int out_size, void* d_ws, size_t ws_size,
                              hipStream_t stream) {
    const float* x   = (const float*)d_in[0];
    const float* bw0 = (const float*)d_in[1];
    const float* sw0 = (const float*)d_in[2];
    const float* ss0 = (const float*)d_in[3];
    const float* bw1 = (const float*)d_in[4];
    const float* sw1 = (const float*)d_in[5];
    const float* ss1 = (const float*)d_in[6];
    const float* dw  = (const float*)d_in[7];
    const float* db  = (const float*)d_in[8];
    float* out = (float*)d_out;

    char* ws = (char*)d_ws;
    __bf16* A0  = (__bf16*)(ws + OFF_A0);
    __bf16* W0  = (__bf16*)(ws + OFF_W0);
    __bf16* A1  = (__bf16*)(ws + OFF_A1);
    __bf16* P0  = (__bf16*)(ws + OFF_P0);
    __bf16* W1  = (__bf16*)(ws + OFF_W1);
    __bf16* P1  = (__bf16*)(ws + OFF_P1);
    __bf16* h1r = (__bf16*)(ws + OFF_H1R);
    __bf16* dwb = (__bf16*)(ws + OFF_DW);

    // Layer 0: K = 9216, splitK=2 -> grid 16x16x2 = 512 blocks (2/CU)
    kan_wprep<<<(H0N * DIN) / 256, 256, 0, stream>>>(bw0, sw0, ss0, W0);
    kan_act<<<(BATCH * DIN) / 256, 256, 0, stream>>>(x, A0);
    gemm_pipe<<<dim3(H0N / 128, BATCH / 256, 2), 256, 0, stream>>>(
        A0, W0, P0, BATCH, H0N, DIN * 9, DIN * 9 / 2);

    // Layer 1: K = 18432, splitK=4 -> grid 8x16x4 = 512 blocks (2/CU)
    kan_wprep<<<(H1N * H0N) / 256, 256, 0, stream>>>(bw1, sw1, ss1, W1);
    kan_act_sum2<<<(BATCH * H0N) / 256, 256, 0, stream>>>(
        P0, P0 + (size_t)BATCH * H0N, A1);
    gemm_pipe<<<dim3(H1N / 128, BATCH / 256, 4), 256, 0, stream>>>(
        A1, W1, P1, BATCH, H1N, H0N * 9, H0N * 9 / 4);

    // relu(sum of 4 bf16 partials) -> bf16
    relu_sum4<<<(BATCH * H1N / 4) / 256, 256, 0, stream>>>(
        P1, (size_t)BATCH * H1N, h1r, BATCH * H1N / 4);

    // Dense: out = h1r @ dw^T + db  (K = 1024)
    f2bf<<<(LOUT * H1N) / 256, 256, 0, stream>>>(dw, dwb, LOUT * H1N);
    gemm_dense<<<dim3(LOUT / 128, BATCH / 128), 256, 0, stream>>>(
        h1r, dwb, out, db, BATCH, LOUT, H1N);
}

// Round 8
// 570.025 us; speedup vs baseline: 1.1508x; 1.0486x over previous
//
#include <hip/hip_runtime.h>
#include <cstdint>
#include <cstddef>

// ---------------------------------------------------------------------------
// KAN encode: x(4096,1024) -> KANLinear(1024->2048) -> KANLinear(2048->1024)
//             -> ReLU -> Dense(1024->512)+bias
// bf16 MFMA GEMMs over augmented K (9 channels per input feature).
// R15: R14 confirmed the GEMM sits at the m97 2-phase plateau (MfmaUtil 39.5%,
//      LDS-read 41%, neither saturated -> phase-granularity serialization).
//      Port the 256^2 8-phase structure (T3+T4+T5) with derived waits:
//        - 256x256 tile, 512 thr, 8 waves (2M x 4N), K-tiles of 64
//        - 2-buffer LDS 128 KiB; 4 sub-phases per K-tile keyed (qm, ks)
//          with balanced reads 8/8/4/4; per phase: reads | stage | barrier |
//          lgkmcnt(0) | sched_barrier | setprio(1) 16xMFMA setprio(0) | barrier
//        - staging of tile t+1 front-loaded in phases 0-1; single vmcnt(0)
//          at phase-3 tail (loads issued ~2 phases earlier -> zero exposure,
//          nothing useful in flight to drain)
//        - 128B-row swizzle: chunk ^= (lr&7); stage source pre-swizzled with
//          c = (lane&7)^(lane>>3)  -> 8-lane groups hit 8 distinct positions
//      bf16 split-K partials kept (R14 win). Non-GEMM kernels unchanged.
// ---------------------------------------------------------------------------

typedef __bf16 bf16x8 __attribute__((ext_vector_type(8)));
typedef __bf16 bf16x4v __attribute__((ext_vector_type(4)));
typedef float floatx4 __attribute__((ext_vector_type(4)));

#define BATCH 4096
#define DIN   1024
#define H0N   2048
#define H1N   1024
#define LOUT  512

// Workspace layout (bytes). P0/P1 bf16.
#define OFF_A0  ((size_t)0)           // bf16 4096*9216  = 75,497,472
#define OFF_W0  ((size_t)75497472)    // bf16 2048*9216  = 37,748,736
#define OFF_A1  ((size_t)0)           // bf16 4096*18432 = 150,994,944 (overlays A0+W0)
#define OFF_P0  ((size_t)150994944)   // bf16 2*4096*2048 = 33,554,432
#define OFF_W1  ((size_t)218103808)   // bf16 1024*18432 = 37,748,736
#define OFF_P1  ((size_t)150994944)   // bf16 4*4096*1024 = 33,554,432 (overlays P0)
#define OFF_H1R ((size_t)218103808)   // bf16 4096*1024  =  8,388,608 (overlays W1)
#define OFF_DW  ((size_t)226492416)   // bf16 512*1024   =  1,048,576

// --------------------------- spline bases ----------------------------------
__device__ __forceinline__ void bspline8(float x, float* out) {
    float b[11];
#pragma unroll
    for (int j = 0; j < 11; ++j) {
        float t0 = (j - 3) * 0.4f - 1.0f;
        float t1 = (j - 2) * 0.4f - 1.0f;
        b[j] = (x >= t0 && x < t1) ? 1.0f : 0.0f;
    }
#pragma unroll
    for (int k = 1; k <= 3; ++k) {
#pragma unroll
        for (int j = 0; j + k < 11; ++j) {
            float tj   = (j - 3) * 0.4f - 1.0f;
            float tj1  = (j - 2) * 0.4f - 1.0f;
            float tjk  = (j + k - 3) * 0.4f - 1.0f;
            float tjk1 = (j + k - 2) * 0.4f - 1.0f;
            float left  = (x - tj)   * (1.0f / (tjk - tj));
            float right = (tjk1 - x) * (1.0f / (tjk1 - tj1));
            b[j] = left * b[j] + right * b[j + 1];
        }
    }
#pragma unroll
    for (int j = 0; j < 8; ++j) out[j] = b[j];
}

// Store 256 threads * 9 bf16 via LDS as 288 coalesced 16B chunks.
__device__ __forceinline__ void coalesced_store9(__bf16* block_dst, const __bf16* vals) {
    __shared__ __bf16 sbuf[256 * 9];
    __bf16* p = &sbuf[threadIdx.x * 9];
#pragma unroll
    for (int j = 0; j < 9; ++j) p[j] = vals[j];
    __syncthreads();
    const uint4* src = (const uint4*)sbuf;
    uint4* dst = (uint4*)block_dst;
    dst[threadIdx.x] = src[threadIdx.x];
    if (threadIdx.x < 32) dst[256 + threadIdx.x] = src[256 + threadIdx.x];
}

__device__ __forceinline__ void act9(float v, __bf16* r) {
    float s = v / (1.0f + __expf(-v));
    float bb[8];
    bspline8(v, bb);
    r[0] = (__bf16)s;
#pragma unroll
    for (int j = 0; j < 8; ++j) r[1 + j] = (__bf16)bb[j];
}

__global__ void kan_act(const float* __restrict__ in, __bf16* __restrict__ out) {
    int base = blockIdx.x * 256;
    float v = in[base + threadIdx.x];
    __bf16 r[9];
    act9(v, r);
    coalesced_store9(out + (size_t)base * 9, r);
}

__global__ void kan_act_sum2(const __bf16* __restrict__ pa, const __bf16* __restrict__ pb,
                             __bf16* __restrict__ out) {
    int base = blockIdx.x * 256;
    int idx = base + threadIdx.x;
    float v = (float)pa[idx] + (float)pb[idx];
    __bf16 r[9];
    act9(v, r);
    coalesced_store9(out + (size_t)base * 9, r);
}

__global__ void relu_sum4(const __bf16* __restrict__ p, size_t stride,
                          __bf16* __restrict__ out, int total4) {
    int idx = blockIdx.x * 256 + threadIdx.x;
    if (idx >= total4) return;
    const bf16x4v* p0 = (const bf16x4v*)p;
    const bf16x4v* p1 = (const bf16x4v*)(p + stride);
    const bf16x4v* p2 = (const bf16x4v*)(p + 2 * stride);
    const bf16x4v* p3 = (const bf16x4v*)(p + 3 * stride);
    bf16x4v a = p0[idx], b = p1[idx], c = p2[idx], d = p3[idx];
    __bf16 r[4];
#pragma unroll
    for (int j = 0; j < 4; ++j) {
        float s = (float)a[j] + (float)b[j] + (float)c[j] + (float)d[j];
        r[j] = (__bf16)fmaxf(s, 0.0f);
    }
    *(uint2*)&out[(size_t)idx * 4] = *(uint2*)r;
}

__global__ void kan_wprep(const float* __restrict__ bw, const float* __restrict__ sw,
                          const float* __restrict__ ss, __bf16* __restrict__ out) {
    int base = blockIdx.x * 256;
    int idx = base + threadIdx.x;
    float b  = bw[idx];
    float sc = ss[idx];
    const float4* sv = (const float4*)(sw + (size_t)idx * 8);
    float4 a = sv[0], c = sv[1];
    __bf16 r[9];
    r[0] = (__bf16)b;
    r[1] = (__bf16)(a.x * sc); r[2] = (__bf16)(a.y * sc);
    r[3] = (__bf16)(a.z * sc); r[4] = (__bf16)(a.w * sc);
    r[5] = (__bf16)(c.x * sc); r[6] = (__bf16)(c.y * sc);
    r[7] = (__bf16)(c.z * sc); r[8] = (__bf16)(c.w * sc);
    coalesced_store9(out + (size_t)base * 9, r);
}

__global__ void f2bf(const float* __restrict__ in, __bf16* __restrict__ out,
                     int total) {
    int idx = blockIdx.x * 256 + threadIdx.x;
    if (idx < total) out[idx] = (__bf16)in[idx];
}

// --------------------------- staging helper --------------------------------
__device__ __forceinline__ void gload_lds16(const void* g, void* l) {
    __builtin_amdgcn_global_load_lds(
        (const __attribute__((address_space(1))) uint32_t*)g,
        (__attribute__((address_space(3))) uint32_t*)l, 16, 0, 0);
}

// ---------------- 8-phase 256x256 MFMA GEMM, 8 waves, 1 blk/CU --------------
// C(M,N) = A(M,K) @ W(N,K)^T, bf16 in, bf16 partial out (split-K per z).
// K consumed in 64-wide tiles; 2-buffer LDS (A,W: 2 x 256x64 each = 128 KiB).
// LDS rows are 128 B (8 chunks of 16 B); swizzle: chunk position
// p = c ^ (row&7). Stage source pre-swizzled: lane writes linear LDS slot
// (row = base + lane>>3, pos = lane&7) from global chunk (lane&7)^(lane>>3).
// Frag reads at chunk (ks*4+kq) ^ (lr&7): each 8-lane quarter-group covers
// 8 distinct 16B positions -> conflict-free by construction.
__global__ __launch_bounds__(512, 2) void gemm8p(
    const __bf16* __restrict__ A, const __bf16* __restrict__ W,
    __bf16* __restrict__ Cout, int M, int N, int K, int Ks) {
    __shared__ __bf16 As[2][256 * 64];        // 2 x 32 KB
    __shared__ __bf16 Ws[2][256 * 64];        // 2 x 32 KB

    const int tid  = threadIdx.x;
    const int lane = tid & 63;
    const int wave = tid >> 6;                // 0..7
    const int wr   = wave >> 2;               // 0..1  (M: 128 rows each)
    const int wc   = wave & 3;                // 0..3  (N: 64 cols each)

    // XCD-aware swizzle (round-robin dispatch: id&7 = XCD); 256 blocks, 1/CU
    const int id    = (blockIdx.z * gridDim.y + blockIdx.y) * gridDim.x + blockIdx.x;
    const int mslab = gridDim.y >> 3;
    const int xcd   = id & 7;
    const int local = id >> 3;
    const int m_off = local % mslab;
    const int rest  = local / mslab;
    const int ntile = rest % gridDim.x;
    const int zt    = rest / gridDim.x;
    const int bm    = (xcd * mslab + m_off) * 256;
    const int bn    = ntile * 256;
    const int kbase = zt * Ks;

    // staging: per call, wave covers 8 rows; lane -> (row += lane>>3, pos lane&7)
    const int srow   = wave * 8 + (lane >> 3);       // 0..63 within 64-row group
    const int schunk = (lane & 7) ^ (lane >> 3);     // pre-swizzled source chunk

    const int lr = lane & 15;
    const int kq = lane >> 4;                        // k sub-chunk 0..3
    const int swz_lo = kq ^ (lr & 7);                // chunk for ks=0: ^ (lr&7)

    floatx4 acc[8][4] = {};

    auto stageA = [&](int buf, int t) {
#pragma unroll
        for (int g = 0; g < 4; ++g) {                // 4 x 64 rows = 256
            gload_lds16(&A[(size_t)(bm + g * 64 + srow) * K + kbase + t * 64 + schunk * 8],
                        &As[buf][(size_t)(g * 64 + wave * 8) * 64]);
        }
    };
    auto stageW = [&](int buf, int t) {
#pragma unroll
        for (int g = 0; g < 4; ++g) {
            gload_lds16(&W[(size_t)(bn + g * 64 + srow) * K + kbase + t * 64 + schunk * 8],
                        &Ws[buf][(size_t)(g * 64 + wave * 8) * 64]);
        }
    };

    const int NT = Ks >> 6;                   // 64-wide K-tiles (72)

    // Prologue: stage tile 0 fully, wait, publish.
    stageA(0, 0);
    stageW(0, 0);
    asm volatile("s_waitcnt vmcnt(0)" ::: "memory");
    __builtin_amdgcn_s_barrier();

    int buf = 0;
#pragma unroll 1
    for (int t = 0; t < NT; ++t) {
        const bool st = (t + 1 < NT);
        bf16x8 wf0[4], wf1[4];

        // ---- phase 0: (qm=0, ks=0); read 4A+4W; stage A(t+1) --------------
        {
            bf16x8 af[4];
            const int cs = swz_lo * 8;                       // ks=0 chunk*8
#pragma unroll
            for (int ft = 0; ft < 4; ++ft)
                af[ft] = *(const bf16x8*)&As[buf][(wr * 128 + ft * 16 + lr) * 64 + ((kq ^ ((lr & 7))) * 8)];
#pragma unroll
            for (int nt = 0; nt < 4; ++nt)
                wf0[nt] = *(const bf16x8*)&Ws[buf][(wc * 64 + nt * 16 + lr) * 64 + cs];
            if (st) stageA(buf ^ 1, t + 1);
            __builtin_amdgcn_s_barrier();
            asm volatile("s_waitcnt lgkmcnt(0)" ::: "memory");
            __builtin_amdgcn_sched_barrier(0);
            __builtin_amdgcn_s_setprio(1);
#pragma unroll
            for (int ft = 0; ft < 4; ++ft)
#pragma unroll
                for (int nt = 0; nt < 4; ++nt)
                    acc[ft][nt] = __builtin_amdgcn_mfma_f32_16x16x32_bf16(
                        af[ft], wf0[nt], acc[ft][nt], 0, 0, 0);
            __builtin_amdgcn_s_setprio(0);
            __builtin_amdgcn_sched_barrier(0);
            __builtin_amdgcn_s_barrier();
        }

        // ---- phase 1: (qm=0, ks=1); read 4A+4W; stage W(t+1) --------------
        {
            bf16x8 af[4];
            const int cs = ((4 + kq) ^ (lr & 7)) * 8;        // ks=1
#pragma unroll
            for (int ft = 0; ft < 4; ++ft)
                af[ft] = *(const bf16x8*)&As[buf][(wr * 128 + ft * 16 + lr) * 64 + cs];
#pragma unroll
            for (int nt = 0; nt < 4; ++nt)
                wf1[nt] = *(const bf16x8*)&Ws[buf][(wc * 64 + nt * 16 + lr) * 64 + cs];
            if (st) stageW(buf ^ 1, t + 1);
            __builtin_amdgcn_s_barrier();
            asm volatile("s_waitcnt lgkmcnt(0)" ::: "memory");
            __builtin_amdgcn_sched_barrier(0);
            __builtin_amdgcn_s_setprio(1);
#pragma unroll
            for (int ft = 0; ft < 4; ++ft)
#pragma unroll
                for (int nt = 0; nt < 4; ++nt)
                    acc[ft][nt] = __builtin_amdgcn_mfma_f32_16x16x32_bf16(
                        af[ft], wf1[nt], acc[ft][nt], 0, 0, 0);
            __builtin_amdgcn_s_setprio(0);
            __builtin_amdgcn_sched_barrier(0);
            __builtin_amdgcn_s_barrier();
        }

        // ---- phase 2: (qm=1, ks=0); read 4A; reuse wf0 --------------------
        {
            bf16x8 af[4];
            const int cs = (kq ^ (lr & 7)) * 8;
#pragma unroll
            for (int ft = 0; ft < 4; ++ft)
                af[ft] = *(const bf16x8*)&As[buf][(wr * 128 + 64 + ft * 16 + lr) * 64 + cs];
            __builtin_amdgcn_s_barrier();
            asm volatile("s_waitcnt lgkmcnt(0)" ::: "memory");
            __builtin_amdgcn_sched_barrier(0);
            __builtin_amdgcn_s_setprio(1);
#pragma unroll
            for (int ft = 0; ft < 4; ++ft)
#pragma unroll
                for (int nt = 0; nt < 4; ++nt)
                    acc[4 + ft][nt] = __builtin_amdgcn_mfma_f32_16x16x32_bf16(
                        af[ft], wf0[nt], acc[4 + ft][nt], 0, 0, 0);
            __builtin_amdgcn_s_setprio(0);
            __builtin_amdgcn_sched_barrier(0);
            __builtin_amdgcn_s_barrier();
        }

        // ---- phase 3: (qm=1, ks=1); read 4A; reuse wf1; tail vm wait ------
        {
            bf16x8 af[4];
            const int cs = ((4 + kq) ^ (lr & 7)) * 8;
#pragma unroll
            for (int ft = 0; ft < 4; ++ft)
                af[ft] = *(const bf16x8*)&As[buf][(wr * 128 + 64 + ft * 16 + lr) * 64 + cs];
            __builtin_amdgcn_s_barrier();
            asm volatile("s_waitcnt lgkmcnt(0)" ::: "memory");
            __builtin_amdgcn_sched_barrier(0);
            __builtin_amdgcn_s_setprio(1);
#pragma unroll
            for (int ft = 0; ft < 4; ++ft)
#pragma unroll
                for (int nt = 0; nt < 4; ++nt)
                    acc[4 + ft][nt] = __builtin_amdgcn_mfma_f32_16x16x32_bf16(
                        af[ft], wf1[nt], acc[4 + ft][nt], 0, 0, 0);
            __builtin_amdgcn_s_setprio(0);
            __builtin_amdgcn_sched_barrier(0);
            // t+1's 8 staging calls were issued in phases 0-1 (~2 phases ago):
            // this wait is effectively free and nothing newer is in flight.
            asm volatile("s_waitcnt vmcnt(0)" ::: "memory");
            __builtin_amdgcn_s_barrier();
        }

        buf ^= 1;
    }

    // C/D layout: col = lane&15, row = (lane>>4)*4 + reg.  bf16 partial store.
    __bf16* Cz = Cout + (size_t)zt * M * N;
    const int col = lane & 15;
    const int rquad = (lane >> 4) * 4;
#pragma unroll
    for (int mf = 0; mf < 8; ++mf) {
#pragma unroll
        for (int nt = 0; nt < 4; ++nt) {
            int n = bn + wc * 64 + nt * 16 + col;
#pragma unroll
            for (int rg = 0; rg < 4; ++rg) {
                int m = bm + wr * 128 + mf * 16 + rquad + rg;
                Cz[(size_t)m * N + n] = (__bf16)acc[mf][nt][rg];
            }
        }
    }
}

// ----------------- 128x128 MFMA GEMM (dense epilogue) ----------------------
__global__ __launch_bounds__(256) void gemm_dense(
    const __bf16* __restrict__ A, const __bf16* __restrict__ W,
    float* __restrict__ Cout, const float* __restrict__ bias,
    int M, int N, int K) {
    constexpr int BK = 32;
    __shared__ __bf16 As[2][128 * BK];
    __shared__ __bf16 Ws[2][128 * BK];

    const int tid  = threadIdx.x;
    const int lane = tid & 63;
    const int wave = tid >> 6;

    const int id    = blockIdx.y * gridDim.x + blockIdx.x;
    const int mslab = gridDim.y >> 3;
    const int xcd   = id & 7;
    const int local = id >> 3;
    const int m_off = local % mslab;
    const int ntile = local / mslab;
    const int bm    = (xcd * mslab + m_off) * 128;
    const int bn    = ntile * 128;

    const int wm = (wave >> 1) * 64;
    const int wn = (wave & 1) * 64;
    const int lr = lane & 15;
    const int kq = lane >> 4;
    const int kssw = (kq ^ ((lr >> 1) & 3)) * 8;

    floatx4 acc[4][4] = {};

    auto stage = [&](int buf, int kpos) {
#pragma unroll
        for (int i = 0; i < 2; ++i) {
            int c = i * 256 + tid;
            int r = c >> 2;
            int q = (c & 3) ^ ((r >> 1) & 3);
            gload_lds16(&A[(size_t)(bm + r) * K + kpos + q * 8],
                        &As[buf][(size_t)(i * 256 + wave * 64) * 8]);
            gload_lds16(&W[(size_t)(bn + r) * K + kpos + q * 8],
                        &Ws[buf][(size_t)(i * 256 + wave * 64) * 8]);
        }
    };

    auto compute = [&](int buf) {
        bf16x8 af[4], wf[4];
#pragma unroll
        for (int t = 0; t < 4; ++t) {
            af[t] = *(const bf16x8*)&As[buf][(wm + t * 16 + lr) * BK + kssw];
            wf[t] = *(const bf16x8*)&Ws[buf][(wn + t * 16 + lr) * BK + kssw];
        }
#pragma unroll
        for (int mt = 0; mt < 4; ++mt)
#pragma unroll
            for (int nt = 0; nt < 4; ++nt)
                acc[mt][nt] = __builtin_amdgcn_mfma_f32_16x16x32_bf16(
                    af[mt], wf[nt], acc[mt][nt], 0, 0, 0);
    };

    stage(0, 0);
    for (int k0 = 0; k0 < K; k0 += 2 * BK) {
        __syncthreads();
        if (k0 + BK < K) stage(1, k0 + BK);
        compute(0);
        __syncthreads();
        if (k0 + 2 * BK < K) stage(0, k0 + 2 * BK);
        compute(1);
    }

    const int col = lane & 15;
    const int rquad = (lane >> 4) * 4;
#pragma unroll
    for (int mt = 0; mt < 4; ++mt) {
#pragma unroll
        for (int nt = 0; nt < 4; ++nt) {
            int n = bn + wn + nt * 16 + col;
#pragma unroll
            for (int rg = 0; rg < 4; ++rg) {
                int m = bm + wm + mt * 16 + rquad + rg;
                Cout[(size_t)m * N + n] = acc[mt][nt][rg] + bias[n];
            }
        }
    }
}

// ---------------------------------------------------------------------------
extern "C" void kernel_launch(void* const* d_in, const int* in_sizes, int n_in,
                              void* d_out, int out_size, void* d_ws, size_t ws_size,
                              hipStream_t stream) {
    const float* x   = (const float*)d_in[0];
    const float* bw0 = (const float*)d_in[1];
    const float* sw0 = (const float*)d_in[2];
    const float* ss0 = (const float*)d_in[3];
    const float* bw1 = (const float*)d_in[4];
    const float* sw1 = (const float*)d_in[5];
    const float* ss1 = (const float*)d_in[6];
    const float* dw  = (const float*)d_in[7];
    const float* db  = (const float*)d_in[8];
    float* out = (float*)d_out;

    char* ws = (char*)d_ws;
    __bf16* A0  = (__bf16*)(ws + OFF_A0);
    __bf16* W0  = (__bf16*)(ws + OFF_W0);
    __bf16* A1  = (__bf16*)(ws + OFF_A1);
    __bf16* P0  = (__bf16*)(ws + OFF_P0);
    __bf16* W1  = (__bf16*)(ws + OFF_W1);
    __bf16* P1  = (__bf16*)(ws + OFF_P1);
    __bf16* h1r = (__bf16*)(ws + OFF_H1R);
    __bf16* dwb = (__bf16*)(ws + OFF_DW);

    // Layer 0: K = 9216, splitK=2 -> grid 8x16x2 = 256 blocks (1/CU)
    kan_wprep<<<(H0N * DIN) / 256, 256, 0, stream>>>(bw0, sw0, ss0, W0);
    kan_act<<<(BATCH * DIN) / 256, 256, 0, stream>>>(x, A0);
    gemm8p<<<dim3(H0N / 256, BATCH / 256, 2), 512, 0, stream>>>(
        A0, W0, P0, BATCH, H0N, DIN * 9, DIN * 9 / 2);

    // Layer 1: K = 18432, splitK=4 -> grid 4x16x4 = 256 blocks (1/CU)
    kan_wprep<<<(H1N * H0N) / 256, 256, 0, stream>>>(bw1, sw1, ss1, W1);
    kan_act_sum2<<<(BATCH * H0N) / 256, 256, 0, stream>>>(
        P0, P0 + (size_t)BATCH * H0N, A1);
    gemm8p<<<dim3(H1N / 256, BATCH / 256, 4), 512, 0, stream>>>(
        A1, W1, P1, BATCH, H1N, H0N * 9, H0N * 9 / 4);

    // relu(sum of 4 bf16 partials) -> bf16
    relu_sum4<<<(BATCH * H1N / 4) / 256, 256, 0, stream>>>(
        P1, (size_t)BATCH * H1N, h1r, BATCH * H1N / 4);

    // Dense: out = h1r @ dw^T + db  (K = 1024)
    f2bf<<<(LOUT * H1N) / 256, 256, 0, stream>>>(dw, dwb, LOUT * H1N);
    gemm_dense<<<dim3(LOUT / 128, BATCH / 128), 256, 0, stream>>>(
        h1r, dwb, out, db, BATCH, LOUT, H1N);
}

// Round 9
// 539.703 us; speedup vs baseline: 1.2154x; 1.0562x over previous
//
#include <hip/hip_runtime.h>
#include <cstdint>
#include <cstddef>

// ---------------------------------------------------------------------------
// KAN encode: x(4096,1024) -> KANLinear(1024->2048) -> KANLinear(2048->1024)
//             -> ReLU -> Dense(1024->512)+bias
// bf16 MFMA GEMMs over augmented K (9 channels per input feature).
// R16: R15 (8-phase lockstep) = 995 TF, MfmaUtil 42.5%. Cycle model: the 8
//      intra-tile barriers force all waves into synchronized read/MFMA
//      windows -> MFMA unit idles during every read window by construction.
//      Intra-tile barriers are semantically unnecessary (no wave writes LDS
//      within a tile; DMA targets buf^1 only; publish = boundary
//      vmcnt(0)+barrier). Delete them; keep phase grouping, setprio, swizzle,
//      staging placement, and ONE boundary sync per K-tile. Waves free-run:
//      wave B's ds_reads overlap wave A's MFMAs (m114), compiler emits
//      fine-grained lgkmcnt. Numerics bit-identical to R15.
// ---------------------------------------------------------------------------

typedef __bf16 bf16x8 __attribute__((ext_vector_type(8)));
typedef __bf16 bf16x4v __attribute__((ext_vector_type(4)));
typedef float floatx4 __attribute__((ext_vector_type(4)));

#define BATCH 4096
#define DIN   1024
#define H0N   2048
#define H1N   1024
#define LOUT  512

// Workspace layout (bytes). P0/P1 bf16.
#define OFF_A0  ((size_t)0)           // bf16 4096*9216  = 75,497,472
#define OFF_W0  ((size_t)75497472)    // bf16 2048*9216  = 37,748,736
#define OFF_A1  ((size_t)0)           // bf16 4096*18432 = 150,994,944 (overlays A0+W0)
#define OFF_P0  ((size_t)150994944)   // bf16 2*4096*2048 = 33,554,432
#define OFF_W1  ((size_t)218103808)   // bf16 1024*18432 = 37,748,736
#define OFF_P1  ((size_t)150994944)   // bf16 4*4096*1024 = 33,554,432 (overlays P0)
#define OFF_H1R ((size_t)218103808)   // bf16 4096*1024  =  8,388,608 (overlays W1)
#define OFF_DW  ((size_t)226492416)   // bf16 512*1024   =  1,048,576

// --------------------------- spline bases ----------------------------------
__device__ __forceinline__ void bspline8(float x, float* out) {
    float b[11];
#pragma unroll
    for (int j = 0; j < 11; ++j) {
        float t0 = (j - 3) * 0.4f - 1.0f;
        float t1 = (j - 2) * 0.4f - 1.0f;
        b[j] = (x >= t0 && x < t1) ? 1.0f : 0.0f;
    }
#pragma unroll
    for (int k = 1; k <= 3; ++k) {
#pragma unroll
        for (int j = 0; j + k < 11; ++j) {
            float tj   = (j - 3) * 0.4f - 1.0f;
            float tj1  = (j - 2) * 0.4f - 1.0f;
            float tjk  = (j + k - 3) * 0.4f - 1.0f;
            float tjk1 = (j + k - 2) * 0.4f - 1.0f;
            float left  = (x - tj)   * (1.0f / (tjk - tj));
            float right = (tjk1 - x) * (1.0f / (tjk1 - tj1));
            b[j] = left * b[j] + right * b[j + 1];
        }
    }
#pragma unroll
    for (int j = 0; j < 8; ++j) out[j] = b[j];
}

// Store 256 threads * 9 bf16 via LDS as 288 coalesced 16B chunks.
__device__ __forceinline__ void coalesced_store9(__bf16* block_dst, const __bf16* vals) {
    __shared__ __bf16 sbuf[256 * 9];
    __bf16* p = &sbuf[threadIdx.x * 9];
#pragma unroll
    for (int j = 0; j < 9; ++j) p[j] = vals[j];
    __syncthreads();
    const uint4* src = (const uint4*)sbuf;
    uint4* dst = (uint4*)block_dst;
    dst[threadIdx.x] = src[threadIdx.x];
    if (threadIdx.x < 32) dst[256 + threadIdx.x] = src[256 + threadIdx.x];
}

__device__ __forceinline__ void act9(float v, __bf16* r) {
    float s = v / (1.0f + __expf(-v));
    float bb[8];
    bspline8(v, bb);
    r[0] = (__bf16)s;
#pragma unroll
    for (int j = 0; j < 8; ++j) r[1 + j] = (__bf16)bb[j];
}

__global__ void kan_act(const float* __restrict__ in, __bf16* __restrict__ out) {
    int base = blockIdx.x * 256;
    float v = in[base + threadIdx.x];
    __bf16 r[9];
    act9(v, r);
    coalesced_store9(out + (size_t)base * 9, r);
}

__global__ void kan_act_sum2(const __bf16* __restrict__ pa, const __bf16* __restrict__ pb,
                             __bf16* __restrict__ out) {
    int base = blockIdx.x * 256;
    int idx = base + threadIdx.x;
    float v = (float)pa[idx] + (float)pb[idx];
    __bf16 r[9];
    act9(v, r);
    coalesced_store9(out + (size_t)base * 9, r);
}

__global__ void relu_sum4(const __bf16* __restrict__ p, size_t stride,
                          __bf16* __restrict__ out, int total4) {
    int idx = blockIdx.x * 256 + threadIdx.x;
    if (idx >= total4) return;
    const bf16x4v* p0 = (const bf16x4v*)p;
    const bf16x4v* p1 = (const bf16x4v*)(p + stride);
    const bf16x4v* p2 = (const bf16x4v*)(p + 2 * stride);
    const bf16x4v* p3 = (const bf16x4v*)(p + 3 * stride);
    bf16x4v a = p0[idx], b = p1[idx], c = p2[idx], d = p3[idx];
    __bf16 r[4];
#pragma unroll
    for (int j = 0; j < 4; ++j) {
        float s = (float)a[j] + (float)b[j] + (float)c[j] + (float)d[j];
        r[j] = (__bf16)fmaxf(s, 0.0f);
    }
    *(uint2*)&out[(size_t)idx * 4] = *(uint2*)r;
}

__global__ void kan_wprep(const float* __restrict__ bw, const float* __restrict__ sw,
                          const float* __restrict__ ss, __bf16* __restrict__ out) {
    int base = blockIdx.x * 256;
    int idx = base + threadIdx.x;
    float b  = bw[idx];
    float sc = ss[idx];
    const float4* sv = (const float4*)(sw + (size_t)idx * 8);
    float4 a = sv[0], c = sv[1];
    __bf16 r[9];
    r[0] = (__bf16)b;
    r[1] = (__bf16)(a.x * sc); r[2] = (__bf16)(a.y * sc);
    r[3] = (__bf16)(a.z * sc); r[4] = (__bf16)(a.w * sc);
    r[5] = (__bf16)(c.x * sc); r[6] = (__bf16)(c.y * sc);
    r[7] = (__bf16)(c.z * sc); r[8] = (__bf16)(c.w * sc);
    coalesced_store9(out + (size_t)base * 9, r);
}

__global__ void f2bf(const float* __restrict__ in, __bf16* __restrict__ out,
                     int total) {
    int idx = blockIdx.x * 256 + threadIdx.x;
    if (idx < total) out[idx] = (__bf16)in[idx];
}

// --------------------------- staging helper --------------------------------
__device__ __forceinline__ void gload_lds16(const void* g, void* l) {
    __builtin_amdgcn_global_load_lds(
        (const __attribute__((address_space(1))) uint32_t*)g,
        (__attribute__((address_space(3))) uint32_t*)l, 16, 0, 0);
}

// ---------------- 256x256 MFMA GEMM, 8 waves, free-run phases ---------------
// C(M,N) = A(M,K) @ W(N,K)^T, bf16 in, bf16 partial out (split-K per z).
// K consumed in 64-wide tiles; 2-buffer LDS (A,W: 2 x 256x64 each = 128 KiB).
// 128B rows, 8 chunks of 16B; swizzle p = c ^ (row&7); stage source
// pre-swizzled with c = (lane&7)^(lane>>3); frag reads conflict-free.
// Sync: ONE {vmcnt(0); s_barrier} per K-tile (publish of tile t+1's DMA).
// No intra-tile barriers: no wave writes LDS within a tile (DMA targets
// buf^1 only), so waves free-run and reads overlap other waves' MFMAs.
__global__ __launch_bounds__(512, 2) void gemm8p(
    const __bf16* __restrict__ A, const __bf16* __restrict__ W,
    __bf16* __restrict__ Cout, int M, int N, int K, int Ks) {
    __shared__ __bf16 As[2][256 * 64];        // 2 x 32 KB
    __shared__ __bf16 Ws[2][256 * 64];        // 2 x 32 KB

    const int tid  = threadIdx.x;
    const int lane = tid & 63;
    const int wave = tid >> 6;                // 0..7
    const int wr   = wave >> 2;               // 0..1  (M: 128 rows each)
    const int wc   = wave & 3;                // 0..3  (N: 64 cols each)

    // XCD-aware swizzle (round-robin dispatch: id&7 = XCD); 256 blocks, 1/CU
    const int id    = (blockIdx.z * gridDim.y + blockIdx.y) * gridDim.x + blockIdx.x;
    const int mslab = gridDim.y >> 3;
    const int xcd   = id & 7;
    const int local = id >> 3;
    const int m_off = local % mslab;
    const int rest  = local / mslab;
    const int ntile = rest % gridDim.x;
    const int zt    = rest / gridDim.x;
    const int bm    = (xcd * mslab + m_off) * 256;
    const int bn    = ntile * 256;
    const int kbase = zt * Ks;

    // staging: per call, wave covers 8 rows; lane -> (row += lane>>3, pos lane&7)
    const int srow   = wave * 8 + (lane >> 3);       // 0..63 within 64-row group
    const int schunk = (lane & 7) ^ (lane >> 3);     // pre-swizzled source chunk

    const int lr = lane & 15;
    const int kq = lane >> 4;                        // k sub-chunk 0..3

    floatx4 acc[8][4] = {};

    auto stageA = [&](int buf, int t) {
#pragma unroll
        for (int g = 0; g < 4; ++g) {                // 4 x 64 rows = 256
            gload_lds16(&A[(size_t)(bm + g * 64 + srow) * K + kbase + t * 64 + schunk * 8],
                        &As[buf][(size_t)(g * 64 + wave * 8) * 64]);
        }
    };
    auto stageW = [&](int buf, int t) {
#pragma unroll
        for (int g = 0; g < 4; ++g) {
            gload_lds16(&W[(size_t)(bn + g * 64 + srow) * K + kbase + t * 64 + schunk * 8],
                        &Ws[buf][(size_t)(g * 64 + wave * 8) * 64]);
        }
    };

    const int NT = Ks >> 6;                   // 64-wide K-tiles

    // Prologue: stage tile 0 fully, wait, publish.
    stageA(0, 0);
    stageW(0, 0);
    asm volatile("s_waitcnt vmcnt(0)" ::: "memory");
    __builtin_amdgcn_s_barrier();

    int buf = 0;
#pragma unroll 1
    for (int t = 0; t < NT; ++t) {
        const bool st = (t + 1 < NT);
        bf16x8 wf0[4], wf1[4];

        // ---- phase 0: (qm=0, ks=0); read 4A+4W; stage A(t+1) --------------
        {
            bf16x8 af[4];
            const int cs0 = (kq ^ (lr & 7)) * 8;             // ks=0 chunk*8
#pragma unroll
            for (int ft = 0; ft < 4; ++ft)
                af[ft] = *(const bf16x8*)&As[buf][(wr * 128 + ft * 16 + lr) * 64 + cs0];
#pragma unroll
            for (int nt = 0; nt < 4; ++nt)
                wf0[nt] = *(const bf16x8*)&Ws[buf][(wc * 64 + nt * 16 + lr) * 64 + cs0];
            if (st) stageA(buf ^ 1, t + 1);
            __builtin_amdgcn_s_setprio(1);
#pragma unroll
            for (int ft = 0; ft < 4; ++ft)
#pragma unroll
                for (int nt = 0; nt < 4; ++nt)
                    acc[ft][nt] = __builtin_amdgcn_mfma_f32_16x16x32_bf16(
                        af[ft], wf0[nt], acc[ft][nt], 0, 0, 0);
            __builtin_amdgcn_s_setprio(0);
        }

        // ---- phase 1: (qm=0, ks=1); read 4A+4W; stage W(t+1) --------------
        {
            bf16x8 af[4];
            const int cs1 = ((4 + kq) ^ (lr & 7)) * 8;       // ks=1
#pragma unroll
            for (int ft = 0; ft < 4; ++ft)
                af[ft] = *(const bf16x8*)&As[buf][(wr * 128 + ft * 16 + lr) * 64 + cs1];
#pragma unroll
            for (int nt = 0; nt < 4; ++nt)
                wf1[nt] = *(const bf16x8*)&Ws[buf][(wc * 64 + nt * 16 + lr) * 64 + cs1];
            if (st) stageW(buf ^ 1, t + 1);
            __builtin_amdgcn_s_setprio(1);
#pragma unroll
            for (int ft = 0; ft < 4; ++ft)
#pragma unroll
                for (int nt = 0; nt < 4; ++nt)
                    acc[ft][nt] = __builtin_amdgcn_mfma_f32_16x16x32_bf16(
                        af[ft], wf1[nt], acc[ft][nt], 0, 0, 0);
            __builtin_amdgcn_s_setprio(0);
        }

        // ---- phase 2: (qm=1, ks=0); read 4A; reuse wf0 --------------------
        {
            bf16x8 af[4];
            const int cs0 = (kq ^ (lr & 7)) * 8;
#pragma unroll
            for (int ft = 0; ft < 4; ++ft)
                af[ft] = *(const bf16x8*)&As[buf][(wr * 128 + 64 + ft * 16 + lr) * 64 + cs0];
            __builtin_amdgcn_s_setprio(1);
#pragma unroll
            for (int ft = 0; ft < 4; ++ft)
#pragma unroll
                for (int nt = 0; nt < 4; ++nt)
                    acc[4 + ft][nt] = __builtin_amdgcn_mfma_f32_16x16x32_bf16(
                        af[ft], wf0[nt], acc[4 + ft][nt], 0, 0, 0);
            __builtin_amdgcn_s_setprio(0);
        }

        // ---- phase 3: (qm=1, ks=1); read 4A; reuse wf1; publish t+1 -------
        {
            bf16x8 af[4];
            const int cs1 = ((4 + kq) ^ (lr & 7)) * 8;
#pragma unroll
            for (int ft = 0; ft < 4; ++ft)
                af[ft] = *(const bf16x8*)&As[buf][(wr * 128 + 64 + ft * 16 + lr) * 64 + cs1];
            __builtin_amdgcn_s_setprio(1);
#pragma unroll
            for (int ft = 0; ft < 4; ++ft)
#pragma unroll
                for (int nt = 0; nt < 4; ++nt)
                    acc[4 + ft][nt] = __builtin_amdgcn_mfma_f32_16x16x32_bf16(
                        af[ft], wf1[nt], acc[4 + ft][nt], 0, 0, 0);
            __builtin_amdgcn_s_setprio(0);
            // Boundary publish: t+1's 8 DMA loads (issued phases 0-1) landed;
            // all intra-tile reads are complete before any wave proceeds.
            asm volatile("s_waitcnt vmcnt(0)" ::: "memory");
            __builtin_amdgcn_s_barrier();
        }

        buf ^= 1;
    }

    // C/D layout: col = lane&15, row = (lane>>4)*4 + reg.  bf16 partial store.
    __bf16* Cz = Cout + (size_t)zt * M * N;
    const int col = lane & 15;
    const int rquad = (lane >> 4) * 4;
#pragma unroll
    for (int mf = 0; mf < 8; ++mf) {
#pragma unroll
        for (int nt = 0; nt < 4; ++nt) {
            int n = bn + wc * 64 + nt * 16 + col;
#pragma unroll
            for (int rg = 0; rg < 4; ++rg) {
                int m = bm + wr * 128 + mf * 16 + rquad + rg;
                Cz[(size_t)m * N + n] = (__bf16)acc[mf][nt][rg];
            }
        }
    }
}

// ----------------- 128x128 MFMA GEMM (dense epilogue) ----------------------
__global__ __launch_bounds__(256) void gemm_dense(
    const __bf16* __restrict__ A, const __bf16* __restrict__ W,
    float* __restrict__ Cout, const float* __restrict__ bias,
    int M, int N, int K) {
    constexpr int BK = 32;
    __shared__ __bf16 As[2][128 * BK];
    __shared__ __bf16 Ws[2][128 * BK];

    const int tid  = threadIdx.x;
    const int lane = tid & 63;
    const int wave = tid >> 6;

    const int id    = blockIdx.y * gridDim.x + blockIdx.x;
    const int mslab = gridDim.y >> 3;
    const int xcd   = id & 7;
    const int local = id >> 3;
    const int m_off = local % mslab;
    const int ntile = local / mslab;
    const int bm    = (xcd * mslab + m_off) * 128;
    const int bn    = ntile * 128;

    const int wm = (wave >> 1) * 64;
    const int wn = (wave & 1) * 64;
    const int lr = lane & 15;
    const int kq = lane >> 4;
    const int kssw = (kq ^ ((lr >> 1) & 3)) * 8;

    floatx4 acc[4][4] = {};

    auto stage = [&](int buf, int kpos) {
#pragma unroll
        for (int i = 0; i < 2; ++i) {
            int c = i * 256 + tid;
            int r = c >> 2;
            int q = (c & 3) ^ ((r >> 1) & 3);
            gload_lds16(&A[(size_t)(bm + r) * K + kpos + q * 8],
                        &As[buf][(size_t)(i * 256 + wave * 64) * 8]);
            gload_lds16(&W[(size_t)(bn + r) * K + kpos + q * 8],
                        &Ws[buf][(size_t)(i * 256 + wave * 64) * 8]);
        }
    };

    auto compute = [&](int buf) {
        bf16x8 af[4], wf[4];
#pragma unroll
        for (int t = 0; t < 4; ++t) {
            af[t] = *(const bf16x8*)&As[buf][(wm + t * 16 + lr) * BK + kssw];
            wf[t] = *(const bf16x8*)&Ws[buf][(wn + t * 16 + lr) * BK + kssw];
        }
#pragma unroll
        for (int mt = 0; mt < 4; ++mt)
#pragma unroll
            for (int nt = 0; nt < 4; ++nt)
                acc[mt][nt] = __builtin_amdgcn_mfma_f32_16x16x32_bf16(
                    af[mt], wf[nt], acc[mt][nt], 0, 0, 0);
    };

    stage(0, 0);
    for (int k0 = 0; k0 < K; k0 += 2 * BK) {
        __syncthreads();
        if (k0 + BK < K) stage(1, k0 + BK);
        compute(0);
        __syncthreads();
        if (k0 + 2 * BK < K) stage(0, k0 + 2 * BK);
        compute(1);
    }

    const int col = lane & 15;
    const int rquad = (lane >> 4) * 4;
#pragma unroll
    for (int mt = 0; mt < 4; ++mt) {
#pragma unroll
        for (int nt = 0; nt < 4; ++nt) {
            int n = bn + wn + nt * 16 + col;
#pragma unroll
            for (int rg = 0; rg < 4; ++rg) {
                int m = bm + wm + mt * 16 + rquad + rg;
                Cout[(size_t)m * N + n] = acc[mt][nt][rg] + bias[n];
            }
        }
    }
}

// ---------------------------------------------------------------------------
extern "C" void kernel_launch(void* const* d_in, const int* in_sizes, int n_in,
                              void* d_out, int out_size, void* d_ws, size_t ws_size,
                              hipStream_t stream) {
    const float* x   = (const float*)d_in[0];
    const float* bw0 = (const float*)d_in[1];
    const float* sw0 = (const float*)d_in[2];
    const float* ss0 = (const float*)d_in[3];
    const float* bw1 = (const float*)d_in[4];
    const float* sw1 = (const float*)d_in[5];
    const float* ss1 = (const float*)d_in[6];
    const float* dw  = (const float*)d_in[7];
    const float* db  = (const float*)d_in[8];
    float* out = (float*)d_out;

    char* ws = (char*)d_ws;
    __bf16* A0  = (__bf16*)(ws + OFF_A0);
    __bf16* W0  = (__bf16*)(ws + OFF_W0);
    __bf16* A1  = (__bf16*)(ws + OFF_A1);
    __bf16* P0  = (__bf16*)(ws + OFF_P0);
    __bf16* W1  = (__bf16*)(ws + OFF_W1);
    __bf16* P1  = (__bf16*)(ws + OFF_P1);
    __bf16* h1r = (__bf16*)(ws + OFF_H1R);
    __bf16* dwb = (__bf16*)(ws + OFF_DW);

    // Layer 0: K = 9216, splitK=2 -> grid 8x16x2 = 256 blocks (1/CU)
    kan_wprep<<<(H0N * DIN) / 256, 256, 0, stream>>>(bw0, sw0, ss0, W0);
    kan_act<<<(BATCH * DIN) / 256, 256, 0, stream>>>(x, A0);
    gemm8p<<<dim3(H0N / 256, BATCH / 256, 2), 512, 0, stream>>>(
        A0, W0, P0, BATCH, H0N, DIN * 9, DIN * 9 / 2);

    // Layer 1: K = 18432, splitK=4 -> grid 4x16x4 = 256 blocks (1/CU)
    kan_wprep<<<(H1N * H0N) / 256, 256, 0, stream>>>(bw1, sw1, ss1, W1);
    kan_act_sum2<<<(BATCH * H0N) / 256, 256, 0, stream>>>(
        P0, P0 + (size_t)BATCH * H0N, A1);
    gemm8p<<<dim3(H1N / 256, BATCH / 256, 4), 512, 0, stream>>>(
        A1, W1, P1, BATCH, H1N, H0N * 9, H0N * 9 / 4);

    // relu(sum of 4 bf16 partials) -> bf16
    relu_sum4<<<(BATCH * H1N / 4) / 256, 256, 0, stream>>>(
        P1, (size_t)BATCH * H1N, h1r, BATCH * H1N / 4);

    // Dense: out = h1r @ dw^T + db  (K = 1024)
    f2bf<<<(LOUT * H1N) / 256, 256, 0, stream>>>(dw, dwb, LOUT * H1N);
    gemm_dense<<<dim3(LOUT / 128, BATCH / 128), 256, 0, stream>>>(
        h1r, dwb, out, db, BATCH, LOUT, H1N);
}